// Round 1
// baseline (3405.800 us; speedup 1.0000x reference)
//
#include <hip/hip_runtime.h>

#define NN 40000
#define DD 64
#define EE 800000
#define NHOP 5
#define NSEM 128

__device__ __forceinline__ float leaky02(float v) { return v > 0.f ? v : 0.2f * v; }

// ---------------- zero kernel ----------------
__global__ void zero_i32(int* __restrict__ p, int n) {
  int i = blockIdx.x * blockDim.x + threadIdx.x;
  if (i < n) p[i] = 0;
}

// ---------------- projection GEMM + bias + relu ----------------
// out[n][64] = relu(X[n][K] @ W[K][64] + bias)
#define PBM 64
#define PBK 32
__global__ __launch_bounds__(256) void proj_gemm_relu(
    const float* __restrict__ X, const float* __restrict__ W,
    const float* __restrict__ bias, float* __restrict__ out, int n, int K)
{
  __shared__ float As[PBM][PBK + 1];
  __shared__ float Bs[PBK][DD];
  int tid = threadIdx.x;
  int tx = tid & 15;   // out quad
  int ty = tid >> 4;   // node quad
  int row0 = blockIdx.x * PBM;
  float acc[4][4] = {{0.f}};
  int nk = (K + PBK - 1) / PBK;
  for (int kt = 0; kt < nk; ++kt) {
    int k0 = kt * PBK;
    for (int i = tid; i < PBM * PBK; i += 256) {
      int r = i >> 5, kk = i & 31;
      int gr = row0 + r, gk = k0 + kk;
      As[r][kk] = (gr < n && gk < K) ? X[(size_t)gr * K + gk] : 0.f;
    }
    for (int i = tid; i < PBK * DD; i += 256) {
      int kk = i >> 6, c = i & 63;
      int gk = k0 + kk;
      Bs[kk][c] = (gk < K) ? W[(size_t)gk * DD + c] : 0.f;
    }
    __syncthreads();
    #pragma unroll
    for (int kk = 0; kk < PBK; ++kk) {
      float a[4], bv[4];
      #pragma unroll
      for (int i = 0; i < 4; ++i) a[i] = As[ty * 4 + i][kk];
      #pragma unroll
      for (int j = 0; j < 4; ++j) bv[j] = Bs[kk][tx * 4 + j];
      #pragma unroll
      for (int i = 0; i < 4; ++i)
        #pragma unroll
        for (int j = 0; j < 4; ++j) acc[i][j] = fmaf(a[i], bv[j], acc[i][j]);
    }
    __syncthreads();
  }
  #pragma unroll
  for (int i = 0; i < 4; ++i) {
    int gr = row0 + ty * 4 + i;
    if (gr < n) {
      #pragma unroll
      for (int j = 0; j < 4; ++j) {
        int c = tx * 4 + j;
        float v = acc[i][j] + bias[c];
        out[(size_t)gr * DD + c] = v > 0.f ? v : 0.f;
      }
    }
  }
}

// ---------------- CSR build ----------------
__global__ void hist_kernel(const int* __restrict__ s, int* __restrict__ counts, int e) {
  int i = blockIdx.x * blockDim.x + threadIdx.x;
  if (i < e) atomicAdd(&counts[s[i]], 1);
}

__global__ __launch_bounds__(1024) void scan_kernel(const int* __restrict__ counts,
    int* __restrict__ rowptr, int* __restrict__ cursor, int n)
{
  __shared__ int tot[1024];
  int t = threadIdx.x;
  int chunk = (n + 1023) / 1024;
  int beg = t * chunk;
  int end = min(beg + chunk, n);
  int ssum = 0;
  for (int i = beg; i < end; ++i) ssum += counts[i];
  tot[t] = ssum;
  __syncthreads();
  for (int off = 1; off < 1024; off <<= 1) {
    int v = (t >= off) ? tot[t - off] : 0;
    __syncthreads();
    tot[t] += v;
    __syncthreads();
  }
  int run = (t == 0) ? 0 : tot[t - 1];
  for (int i = beg; i < end; ++i) {
    rowptr[i] = run;
    cursor[i] = run;
    run += counts[i];
  }
  if (t == 1023) rowptr[n] = tot[1023];
}

__global__ void scatter_kernel(const int* __restrict__ s, const int* __restrict__ tt,
    int* __restrict__ cursor, int* __restrict__ tsorted, int e)
{
  int i = blockIdx.x * blockDim.x + threadIdx.x;
  if (i < e) {
    int pos = atomicAdd(&cursor[s[i]], 1);
    tsorted[pos] = tt[i];
  }
}

// ---------------- per-hop per-node dot products ----------------
// Computes for all 4 relations: x1 (src), w2=exp(leaky(x@(a1+a2))) (src), h1 (tgt)
__global__ __launch_bounds__(256) void dots_kernel(
    const float* __restrict__ xA, const float* __restrict__ xP,
    const float* __restrict__ hA, const float* __restrict__ hP,
    const float* __restrict__ a1ap, const float* __restrict__ a2ap,
    const float* __restrict__ a1aa, const float* __restrict__ a2aa,
    const float* __restrict__ a1pa, const float* __restrict__ a2pa,
    const float* __restrict__ a1pp, const float* __restrict__ a2pp,
    float* __restrict__ x1ap, float* __restrict__ w2ap, float* __restrict__ h1ap,
    float* __restrict__ x1aa, float* __restrict__ w2aa, float* __restrict__ h1aa,
    float* __restrict__ x1pa, float* __restrict__ w2pa, float* __restrict__ h1pa,
    float* __restrict__ x1pp, float* __restrict__ w2pp, float* __restrict__ h1pp,
    int n)
{
  __shared__ float A[8][DD];
  int tid = threadIdx.x;
  {
    const float* srcs[8] = {a1ap, a2ap, a1aa, a2aa, a1pa, a2pa, a1pp, a2pp};
    for (int i = tid; i < 8 * DD; i += 256) A[i >> 6][i & 63] = srcs[i >> 6][i & 63];
  }
  __syncthreads();
  int j = blockIdx.x * 256 + tid;
  if (j >= n) return;
  const float4* xa4 = (const float4*)(xA + (size_t)j * DD);
  const float4* xp4 = (const float4*)(xP + (size_t)j * DD);
  const float4* ha4 = (const float4*)(hA + (size_t)j * DD);
  const float4* hp4 = (const float4*)(hP + (size_t)j * DD);
  float s_a1ap = 0.f, s_a2ap = 0.f, s_a1aa = 0.f, s_a2aa = 0.f;
  float s_p1pa = 0.f, s_p2pa = 0.f, s_p1pp = 0.f, s_p2pp = 0.f;
  float s_hap = 0.f, s_haa = 0.f, s_hpa = 0.f, s_hpp = 0.f;
  #pragma unroll
  for (int d0 = 0; d0 < 16; ++d0) {
    float4 xa = xa4[d0], xp = xp4[d0], ha = ha4[d0], hp = hp4[d0];
    #pragma unroll
    for (int c = 0; c < 4; ++c) {
      int d = d0 * 4 + c;
      float xav = (&xa.x)[c], xpv = (&xp.x)[c], hav = (&ha.x)[c], hpv = (&hp.x)[c];
      s_a1ap = fmaf(xav, A[0][d], s_a1ap);
      s_a2ap = fmaf(xav, A[1][d], s_a2ap);
      s_a1aa = fmaf(xav, A[2][d], s_a1aa);
      s_a2aa = fmaf(xav, A[3][d], s_a2aa);
      s_p1pa = fmaf(xpv, A[4][d], s_p1pa);
      s_p2pa = fmaf(xpv, A[5][d], s_p2pa);
      s_p1pp = fmaf(xpv, A[6][d], s_p1pp);
      s_p2pp = fmaf(xpv, A[7][d], s_p2pp);
      s_hap = fmaf(hpv, A[1][d], s_hap);   // h1_ap = hP . a2_ap
      s_haa = fmaf(hav, A[3][d], s_haa);   // h1_aa = hA . a2_aa
      s_hpa = fmaf(hav, A[5][d], s_hpa);   // h1_pa = hA . a2_pa
      s_hpp = fmaf(hpv, A[7][d], s_hpp);   // h1_pp = hP . a2_pp
    }
  }
  x1ap[j] = s_a1ap; w2ap[j] = __expf(leaky02(s_a1ap + s_a2ap)); h1ap[j] = s_hap;
  x1aa[j] = s_a1aa; w2aa[j] = __expf(leaky02(s_a1aa + s_a2aa)); h1aa[j] = s_haa;
  x1pa[j] = s_p1pa; w2pa[j] = __expf(leaky02(s_p1pa + s_p2pa)); h1pa[j] = s_hpa;
  x1pp[j] = s_p1pp; w2pp[j] = __expf(leaky02(s_p1pp + s_p2pp)); h1pp[j] = s_hpp;
}

// ---------------- edge aggregation (one wave per source node) ----------------
__global__ __launch_bounds__(256) void agg_kernel(
    const float* __restrict__ x, const float* __restrict__ h,
    const float* __restrict__ x1, const float* __restrict__ w2v,
    const float* __restrict__ h1,
    const int* __restrict__ rowptr, const int* __restrict__ tsorted,
    float* __restrict__ out, int n)
{
  int wid = (blockIdx.x * blockDim.x + threadIdx.x) >> 6;
  int lane = threadIdx.x & 63;
  if (wid >= n) return;
  int beg = rowptr[wid], end = rowptr[wid + 1];
  float x1i = x1[wid];
  float acc = 0.f, wsum = 0.f;
  for (int e = beg; e < end; ++e) {
    int t = tsorted[e];
    float scv = leaky02(x1i + h1[t]);
    float w = __expf(scv);
    wsum += w;
    acc = fmaf(w, h[(size_t)t * DD + lane], acc);
  }
  float w2 = w2v[wid];
  float den = wsum + w2;
  float num = fmaf(w2, x[(size_t)wid * DD + lane], acc);
  out[(size_t)wid * DD + lane] = num / den;
}

// ---------------- semantic attention: per-node scores ----------------
__device__ __forceinline__ float tanh_fast(float x) {
  // tanh(x) = 1 - 2/(exp(2x)+1); saturates correctly at +-inf
  return 1.f - 2.f / (__expf(2.f * x) + 1.f);
}

__global__ __launch_bounds__(256) void sem_sc_kernel(
    const float* __restrict__ e0, const float* __restrict__ e1,
    const float* __restrict__ W, const float* __restrict__ b,
    const float* __restrict__ q, float* __restrict__ sc, int n)
{
  __shared__ float Ws[DD * NSEM];
  __shared__ float zs[2][2][DD];
  __shared__ float red[2][2][2];
  int tid = threadIdx.x;
  for (int i = tid; i < DD * NSEM; i += 256) Ws[i] = W[i];
  int slot = tid >> 7;
  int k = tid & 127;
  float bk = b[k], qk = q[k];
  int base = blockIdx.x * 32;
  for (int it = 0; it < 16; ++it) {
    // stage z for 2 nodes x 2 relations
    {
      int nslot = tid >> 7, m = (tid >> 6) & 1, d = tid & 63;
      int node = base + it * 2 + nslot;
      zs[nslot][m][d] = (m == 0 ? e0 : e1)[(size_t)node * DD + d];
    }
    __syncthreads();
    float acc0 = bk, acc1 = bk;
    #pragma unroll
    for (int d = 0; d < DD; ++d) {
      float w = Ws[d * NSEM + k];
      acc0 = fmaf(zs[slot][0][d], w, acc0);
      acc1 = fmaf(zs[slot][1][d], w, acc1);
    }
    float c0 = tanh_fast(acc0) * qk;
    float c1 = tanh_fast(acc1) * qk;
    #pragma unroll
    for (int off = 32; off; off >>= 1) {
      c0 += __shfl_xor(c0, off);
      c1 += __shfl_xor(c1, off);
    }
    int lane = tid & 63, half = (tid >> 6) & 1;
    if (lane == 0) { red[slot][0][half] = c0; red[slot][1][half] = c1; }
    __syncthreads();
    if (k == 0) {
      int node = base + it * 2 + slot;
      sc[(size_t)node * 2 + 0] = red[slot][0][0] + red[slot][0][1];
      sc[(size_t)node * 2 + 1] = red[slot][1][0] + red[slot][1][1];
    }
    __syncthreads();
  }
}

// deterministic mean + softmax -> beta[2]
__global__ __launch_bounds__(1024) void beta_kernel(const float* __restrict__ sc,
    float* __restrict__ beta, int n)
{
  __shared__ float s0[1024], s1[1024];
  int t = threadIdx.x;
  float a0 = 0.f, a1 = 0.f;
  for (int i = t; i < n; i += 1024) { a0 += sc[(size_t)i * 2]; a1 += sc[(size_t)i * 2 + 1]; }
  s0[t] = a0; s1[t] = a1;
  __syncthreads();
  for (int off = 512; off; off >>= 1) {
    if (t < off) { s0[t] += s0[t + off]; s1[t] += s1[t + off]; }
    __syncthreads();
  }
  if (t == 0) {
    float m0 = s0[0] / n, m1 = s1[0] / n;
    float mx = fmaxf(m0, m1);
    float x0 = __expf(m0 - mx), x1 = __expf(m1 - mx);
    float inv = 1.f / (x0 + x1);
    beta[0] = x0 * inv;
    beta[1] = x1 * inv;
  }
}

__global__ void combine_elu_kernel(const float* __restrict__ e0, const float* __restrict__ e1,
    const float* __restrict__ beta, float* __restrict__ hnew, int total)
{
  int i = blockIdx.x * blockDim.x + threadIdx.x;
  if (i < total) {
    float v = beta[0] * e0[i] + beta[1] * e1[i];
    hnew[i] = v > 0.f ? v : (__expf(v) - 1.f);
  }
}

// ---------------- final projection [40000,64]@[64,4] + b2 ----------------
__global__ void final_kernel(const float* __restrict__ hA, const float* __restrict__ W2,
    const float* __restrict__ b2, float* __restrict__ out, int n)
{
  int j = blockIdx.x * blockDim.x + threadIdx.x;
  if (j >= n) return;
  float acc0 = b2[0], acc1 = b2[1], acc2 = b2[2], acc3 = b2[3];
  const float* hrow = hA + (size_t)j * DD;
  #pragma unroll
  for (int d = 0; d < DD; ++d) {
    float v = hrow[d];
    acc0 = fmaf(v, W2[d * 4 + 0], acc0);
    acc1 = fmaf(v, W2[d * 4 + 1], acc1);
    acc2 = fmaf(v, W2[d * 4 + 2], acc2);
    acc3 = fmaf(v, W2[d * 4 + 3], acc3);
  }
  out[(size_t)j * 4 + 0] = acc0;
  out[(size_t)j * 4 + 1] = acc1;
  out[(size_t)j * 4 + 2] = acc2;
  out[(size_t)j * 4 + 3] = acc3;
}

extern "C" void kernel_launch(void* const* d_in, const int* in_sizes, int n_in,
                              void* d_out, int out_size, void* d_ws, size_t ws_size,
                              hipStream_t stream)
{
  const float* x_author = (const float*)d_in[0];
  const float* x_paper  = (const float*)d_in[1];
  const float* W1_a = (const float*)d_in[2];
  const float* b1_a = (const float*)d_in[3];
  const float* W1_p = (const float*)d_in[4];
  const float* b1_p = (const float*)d_in[5];
  const float* a1_ap = (const float*)d_in[6];
  const float* a2_ap = (const float*)d_in[7];
  const float* a1_aa = (const float*)d_in[8];
  const float* a2_aa = (const float*)d_in[9];
  const float* a1_pa = (const float*)d_in[10];
  const float* a2_pa = (const float*)d_in[11];
  const float* a1_pp = (const float*)d_in[12];
  const float* a2_pp = (const float*)d_in[13];
  const float* semW_a = (const float*)d_in[14];
  const float* semb_a = (const float*)d_in[15];
  const float* semq_a = (const float*)d_in[16];
  const float* semW_p = (const float*)d_in[17];
  const float* semb_p = (const float*)d_in[18];
  const float* semq_p = (const float*)d_in[19];
  const float* W2 = (const float*)d_in[20];
  const float* b2 = (const float*)d_in[21];
  const int* ei[4] = {(const int*)d_in[22], (const int*)d_in[23],
                      (const int*)d_in[24], (const int*)d_in[25]};

  // ---- workspace carve ----
  char* w = (char*)d_ws;
  auto alloc = [&](size_t bytes) -> void* {
    void* p = (void*)w;
    w += (bytes + 255) & ~(size_t)255;
    return p;
  };
  const size_t matB = (size_t)NN * DD * sizeof(float);
  float* xA  = (float*)alloc(matB);
  float* xP  = (float*)alloc(matB);
  float* hAb[2] = {(float*)alloc(matB), (float*)alloc(matB)};
  float* hPb[2] = {(float*)alloc(matB), (float*)alloc(matB)};
  float* e0  = (float*)alloc(matB);
  float* e1  = (float*)alloc(matB);
  int* rowptr[4]; int* tsorted[4];
  for (int r = 0; r < 4; ++r) {
    rowptr[r]  = (int*)alloc((NN + 1) * sizeof(int));
    tsorted[r] = (int*)alloc((size_t)EE * sizeof(int));
  }
  int* counts = (int*)alloc(NN * sizeof(int));
  int* cursor = (int*)alloc(NN * sizeof(int));
  float* x1b[4], *w2b[4], *h1b[4];
  for (int r = 0; r < 4; ++r) {
    x1b[r] = (float*)alloc(NN * sizeof(float));
    w2b[r] = (float*)alloc(NN * sizeof(float));
    h1b[r] = (float*)alloc(NN * sizeof(float));
  }
  float* scbuf = (float*)alloc((size_t)NN * 2 * sizeof(float));
  float* betaA = (float*)alloc(64);
  float* betaP = (float*)alloc(64);

  // ---- projections ----
  proj_gemm_relu<<<NN / PBM, 256, 0, stream>>>(x_author, W1_a, b1_a, xA, NN, 334);
  proj_gemm_relu<<<NN / PBM, 256, 0, stream>>>(x_paper,  W1_p, b1_p, xP, NN, 512);

  // ---- CSR build per relation (reuses counts/cursor; stream-ordered) ----
  const int EB = (EE + 255) / 256;
  for (int r = 0; r < 4; ++r) {
    const int* s = ei[r];
    const int* t = ei[r] + EE;
    zero_i32<<<(NN + 255) / 256, 256, 0, stream>>>(counts, NN);
    hist_kernel<<<EB, 256, 0, stream>>>(s, counts, EE);
    scan_kernel<<<1, 1024, 0, stream>>>(counts, rowptr[r], cursor, NN);
    scatter_kernel<<<EB, 256, 0, stream>>>(s, t, cursor, tsorted[r], EE);
  }

  // ---- hop loop ----
  const int AGG_GRID = (NN * 64) / 256;
  for (int i = 0; i < NHOP; ++i) {
    const float* hAc = (i == 0) ? xA : hAb[(i - 1) & 1];
    const float* hPc = (i == 0) ? xP : hPb[(i - 1) & 1];
    float* hAn = hAb[i & 1];
    float* hPn = hPb[i & 1];

    dots_kernel<<<(NN + 255) / 256, 256, 0, stream>>>(
        xA, xP, hAc, hPc,
        a1_ap + i * DD, a2_ap + i * DD, a1_aa + i * DD, a2_aa + i * DD,
        a1_pa + i * DD, a2_pa + i * DD, a1_pp + i * DD, a2_pp + i * DD,
        x1b[0], w2b[0], h1b[0], x1b[1], w2b[1], h1b[1],
        x1b[2], w2b[2], h1b[2], x1b[3], w2b[3], h1b[3], NN);

    // author side: relations ap (h=hP), aa (h=hA)
    agg_kernel<<<AGG_GRID, 256, 0, stream>>>(xA, hPc, x1b[0], w2b[0], h1b[0],
                                             rowptr[0], tsorted[0], e0, NN);
    agg_kernel<<<AGG_GRID, 256, 0, stream>>>(xA, hAc, x1b[1], w2b[1], h1b[1],
                                             rowptr[1], tsorted[1], e1, NN);
    sem_sc_kernel<<<NN / 32, 256, 0, stream>>>(e0, e1, semW_a + (size_t)i * DD * NSEM,
                                               semb_a + i * NSEM, semq_a + i * NSEM, scbuf, NN);
    beta_kernel<<<1, 1024, 0, stream>>>(scbuf, betaA, NN);
    combine_elu_kernel<<<AGG_GRID, 256, 0, stream>>>(e0, e1, betaA, hAn, NN * DD);

    // paper side: relations pa (h=hA old), pp (h=hP old)
    agg_kernel<<<AGG_GRID, 256, 0, stream>>>(xP, hAc, x1b[2], w2b[2], h1b[2],
                                             rowptr[2], tsorted[2], e0, NN);
    agg_kernel<<<AGG_GRID, 256, 0, stream>>>(xP, hPc, x1b[3], w2b[3], h1b[3],
                                             rowptr[3], tsorted[3], e1, NN);
    sem_sc_kernel<<<NN / 32, 256, 0, stream>>>(e0, e1, semW_p + (size_t)i * DD * NSEM,
                                               semb_p + i * NSEM, semq_p + i * NSEM, scbuf, NN);
    beta_kernel<<<1, 1024, 0, stream>>>(scbuf, betaP, NN);
    combine_elu_kernel<<<AGG_GRID, 256, 0, stream>>>(e0, e1, betaP, hPn, NN * DD);
  }

  // final hA buffer after 5 hops: hAb[(NHOP-1)&1] = hAb[0]
  final_kernel<<<(NN + 255) / 256, 256, 0, stream>>>(hAb[(NHOP - 1) & 1], W2, b2,
                                                     (float*)d_out, NN);
}

// Round 2
// 1854.664 us; speedup vs baseline: 1.8363x; 1.8363x over previous
//
#include <hip/hip_runtime.h>

#define NN 40000
#define DD 64
#define EE 800000
#define NHOP 5
#define NSEM 128

__device__ __forceinline__ float leaky02(float v) { return v > 0.f ? v : 0.2f * v; }
__device__ __forceinline__ float tanh_fast(float x) {
  return 1.f - 2.f / (__expf(2.f * x) + 1.f);
}

// ---------------- zero kernel ----------------
__global__ void zero_i32(int* __restrict__ p, int n) {
  int i = blockIdx.x * blockDim.x + threadIdx.x;
  if (i < n) p[i] = 0;
}

// ---------------- projection GEMM + bias + relu ----------------
// out[n][64] = relu(X[n][K] @ W[K][64] + bias); 64x64 tile, BK=64, 512 thr
#define PBM 64
#define PBK 64
__global__ __launch_bounds__(512) void proj_gemm_relu(
    const float* __restrict__ X, const float* __restrict__ W,
    const float* __restrict__ bias, float* __restrict__ out, int n, int K)
{
  __shared__ float As[PBM][PBK + 1];
  __shared__ float Bs[PBK][DD];
  int tid = threadIdx.x;
  int tx = tid & 15;        // col quad (4 cols)
  int ty = tid >> 4;        // row pair (2 rows), 0..31
  int row0 = blockIdx.x * PBM;
  float acc[2][4] = {{0.f}};
  int nk = (K + PBK - 1) / PBK;
  for (int kt = 0; kt < nk; ++kt) {
    int k0 = kt * PBK;
    #pragma unroll
    for (int j = 0; j < 8; ++j) {
      int idx = tid + j * 512;
      int r = idx >> 6, c = idx & 63;
      int gk = k0 + c;
      As[r][c] = (gk < K) ? X[(size_t)(row0 + r) * K + gk] : 0.f;
    }
    #pragma unroll
    for (int j = 0; j < 2; ++j) {
      int idx = tid + j * 512;          // float4 index
      int r = idx >> 4, c4 = idx & 15;
      int gk = k0 + r;
      float4 v = (gk < K) ? ((const float4*)(W + (size_t)gk * DD))[c4]
                          : make_float4(0.f, 0.f, 0.f, 0.f);
      ((float4*)&Bs[r][0])[c4] = v;
    }
    __syncthreads();
    #pragma unroll 8
    for (int kk = 0; kk < PBK; ++kk) {
      float a0 = As[ty * 2][kk];
      float a1 = As[ty * 2 + 1][kk];
      float4 bv = ((float4*)&Bs[kk][0])[tx];
      acc[0][0] = fmaf(a0, bv.x, acc[0][0]);
      acc[0][1] = fmaf(a0, bv.y, acc[0][1]);
      acc[0][2] = fmaf(a0, bv.z, acc[0][2]);
      acc[0][3] = fmaf(a0, bv.w, acc[0][3]);
      acc[1][0] = fmaf(a1, bv.x, acc[1][0]);
      acc[1][1] = fmaf(a1, bv.y, acc[1][1]);
      acc[1][2] = fmaf(a1, bv.z, acc[1][2]);
      acc[1][3] = fmaf(a1, bv.w, acc[1][3]);
    }
    __syncthreads();
  }
  float4 bb = ((const float4*)bias)[tx];
  #pragma unroll
  for (int i = 0; i < 2; ++i) {
    int gr = row0 + ty * 2 + i;
    float4 v;
    v.x = fmaxf(acc[i][0] + bb.x, 0.f);
    v.y = fmaxf(acc[i][1] + bb.y, 0.f);
    v.z = fmaxf(acc[i][2] + bb.z, 0.f);
    v.w = fmaxf(acc[i][3] + bb.w, 0.f);
    ((float4*)(out + (size_t)gr * DD))[tx] = v;
  }
}

// ---------------- CSR build (4 relations batched) ----------------
__global__ void hist4_kernel(const int* __restrict__ e0, const int* __restrict__ e1,
    const int* __restrict__ e2, const int* __restrict__ e3,
    int* __restrict__ counts, int e, int n)
{
  int rel = blockIdx.y;
  const int* s = rel == 0 ? e0 : rel == 1 ? e1 : rel == 2 ? e2 : e3;
  int i = blockIdx.x * blockDim.x + threadIdx.x;
  if (i < e) atomicAdd(&counts[(size_t)rel * n + s[i]], 1);
}

__global__ __launch_bounds__(1024) void scan4_kernel(const int* __restrict__ counts,
    int* __restrict__ rp0, int* __restrict__ rp1, int* __restrict__ rp2,
    int* __restrict__ rp3, int* __restrict__ cursor, int n)
{
  int rel = blockIdx.x;
  const int* c = counts + (size_t)rel * n;
  int* cur = cursor + (size_t)rel * n;
  int* rowptr = rel == 0 ? rp0 : rel == 1 ? rp1 : rel == 2 ? rp2 : rp3;
  __shared__ int tot[1024];
  int t = threadIdx.x;
  int chunk = (n + 1023) / 1024;
  int beg = t * chunk;
  int end = min(beg + chunk, n);
  int ssum = 0;
  for (int i = beg; i < end; ++i) ssum += c[i];
  tot[t] = ssum;
  __syncthreads();
  for (int off = 1; off < 1024; off <<= 1) {
    int v = (t >= off) ? tot[t - off] : 0;
    __syncthreads();
    tot[t] += v;
    __syncthreads();
  }
  int run = (t == 0) ? 0 : tot[t - 1];
  for (int i = beg; i < end; ++i) {
    rowptr[i] = run;
    cur[i] = run;
    run += c[i];
  }
  if (t == 1023) rowptr[n] = tot[1023];
}

__global__ void scatter4_kernel(const int* __restrict__ e0, const int* __restrict__ e1,
    const int* __restrict__ e2, const int* __restrict__ e3,
    int* __restrict__ cursor,
    int* __restrict__ ts0, int* __restrict__ ts1, int* __restrict__ ts2,
    int* __restrict__ ts3, int e, int n)
{
  int rel = blockIdx.y;
  const int* s = rel == 0 ? e0 : rel == 1 ? e1 : rel == 2 ? e2 : e3;
  int* ts = rel == 0 ? ts0 : rel == 1 ? ts1 : rel == 2 ? ts2 : ts3;
  int i = blockIdx.x * blockDim.x + threadIdx.x;
  if (i < e) {
    int pos = atomicAdd(&cursor[(size_t)rel * n + s[i]], 1);
    ts[pos] = s[e + i - i] == s[i] ? (rel == 0 ? e0 : rel == 1 ? e1 : rel == 2 ? e2 : e3)[e + i] : 0;
    // (the above indexes target row: ei[rel][1][i] == s-ptr + e + i)
    ts[pos] = (rel == 0 ? e0 : rel == 1 ? e1 : rel == 2 ? e2 : e3)[e + i];
  }
}

// ---------------- per-hop per-node dot products ----------------
__global__ __launch_bounds__(256) void dots_kernel(
    const float* __restrict__ xA, const float* __restrict__ xP,
    const float* __restrict__ hA, const float* __restrict__ hP,
    const float* __restrict__ a1ap, const float* __restrict__ a2ap,
    const float* __restrict__ a1aa, const float* __restrict__ a2aa,
    const float* __restrict__ a1pa, const float* __restrict__ a2pa,
    const float* __restrict__ a1pp, const float* __restrict__ a2pp,
    float* __restrict__ x1ap, float* __restrict__ w2ap, float* __restrict__ h1ap,
    float* __restrict__ x1aa, float* __restrict__ w2aa, float* __restrict__ h1aa,
    float* __restrict__ x1pa, float* __restrict__ w2pa, float* __restrict__ h1pa,
    float* __restrict__ x1pp, float* __restrict__ w2pp, float* __restrict__ h1pp,
    int n)
{
  __shared__ float A[8][DD];
  int tid = threadIdx.x;
  {
    const float* srcs[8] = {a1ap, a2ap, a1aa, a2aa, a1pa, a2pa, a1pp, a2pp};
    for (int i = tid; i < 8 * DD; i += 256) A[i >> 6][i & 63] = srcs[i >> 6][i & 63];
  }
  __syncthreads();
  int j = blockIdx.x * 256 + tid;
  if (j >= n) return;
  const float4* xa4 = (const float4*)(xA + (size_t)j * DD);
  const float4* xp4 = (const float4*)(xP + (size_t)j * DD);
  const float4* ha4 = (const float4*)(hA + (size_t)j * DD);
  const float4* hp4 = (const float4*)(hP + (size_t)j * DD);
  float s_a1ap = 0.f, s_a2ap = 0.f, s_a1aa = 0.f, s_a2aa = 0.f;
  float s_p1pa = 0.f, s_p2pa = 0.f, s_p1pp = 0.f, s_p2pp = 0.f;
  float s_hap = 0.f, s_haa = 0.f, s_hpa = 0.f, s_hpp = 0.f;
  #pragma unroll
  for (int d0 = 0; d0 < 16; ++d0) {
    float4 xa = xa4[d0], xp = xp4[d0], ha = ha4[d0], hp = hp4[d0];
    #pragma unroll
    for (int c = 0; c < 4; ++c) {
      int d = d0 * 4 + c;
      float xav = (&xa.x)[c], xpv = (&xp.x)[c], hav = (&ha.x)[c], hpv = (&hp.x)[c];
      s_a1ap = fmaf(xav, A[0][d], s_a1ap);
      s_a2ap = fmaf(xav, A[1][d], s_a2ap);
      s_a1aa = fmaf(xav, A[2][d], s_a1aa);
      s_a2aa = fmaf(xav, A[3][d], s_a2aa);
      s_p1pa = fmaf(xpv, A[4][d], s_p1pa);
      s_p2pa = fmaf(xpv, A[5][d], s_p2pa);
      s_p1pp = fmaf(xpv, A[6][d], s_p1pp);
      s_p2pp = fmaf(xpv, A[7][d], s_p2pp);
      s_hap = fmaf(hpv, A[1][d], s_hap);
      s_haa = fmaf(hav, A[3][d], s_haa);
      s_hpa = fmaf(hav, A[5][d], s_hpa);
      s_hpp = fmaf(hpv, A[7][d], s_hpp);
    }
  }
  x1ap[j] = s_a1ap; w2ap[j] = __expf(leaky02(s_a1ap + s_a2ap)); h1ap[j] = s_hap;
  x1aa[j] = s_a1aa; w2aa[j] = __expf(leaky02(s_a1aa + s_a2aa)); h1aa[j] = s_haa;
  x1pa[j] = s_p1pa; w2pa[j] = __expf(leaky02(s_p1pa + s_p2pa)); h1pa[j] = s_hpa;
  x1pp[j] = s_p1pp; w2pp[j] = __expf(leaky02(s_p1pp + s_p2pp)); h1pp[j] = s_hpp;
}

// ---------------- fused edge aggregation: 4 relations, one wave per node ----------------
struct AggRel {
  const float* x; const float* h; const float* x1; const float* w2; const float* h1;
  const int* rowptr; const int* tsorted; float* out;
};

__global__ __launch_bounds__(256) void agg4_kernel(AggRel r0, AggRel r1, AggRel r2,
                                                   AggRel r3, int n)
{
  AggRel R;
  switch (blockIdx.y) {
    case 0: R = r0; break;
    case 1: R = r1; break;
    case 2: R = r2; break;
    default: R = r3; break;
  }
  int wid = (blockIdx.x * blockDim.x + threadIdx.x) >> 6;
  int lane = threadIdx.x & 63;
  if (wid >= n) return;
  int beg = R.rowptr[wid], end = R.rowptr[wid + 1];
  float x1i = R.x1[wid];
  float acc = 0.f, wsum = 0.f;
  int e = beg;
  for (; e + 4 <= end; e += 4) {
    int t0 = R.tsorted[e], t1 = R.tsorted[e + 1];
    int t2 = R.tsorted[e + 2], t3 = R.tsorted[e + 3];
    float s0 = R.h1[t0], s1 = R.h1[t1], s2 = R.h1[t2], s3 = R.h1[t3];
    float v0 = R.h[(size_t)t0 * DD + lane];
    float v1 = R.h[(size_t)t1 * DD + lane];
    float v2 = R.h[(size_t)t2 * DD + lane];
    float v3 = R.h[(size_t)t3 * DD + lane];
    float w0 = __expf(leaky02(x1i + s0));
    float w1 = __expf(leaky02(x1i + s1));
    float w2_ = __expf(leaky02(x1i + s2));
    float w3 = __expf(leaky02(x1i + s3));
    wsum += (w0 + w1) + (w2_ + w3);
    acc = fmaf(w0, v0, acc);
    acc = fmaf(w1, v1, acc);
    acc = fmaf(w2_, v2, acc);
    acc = fmaf(w3, v3, acc);
  }
  for (; e < end; ++e) {
    int t = R.tsorted[e];
    float w = __expf(leaky02(x1i + R.h1[t]));
    wsum += w;
    acc = fmaf(w, R.h[(size_t)t * DD + lane], acc);
  }
  float w2v = R.w2[wid];
  float num = fmaf(w2v, R.x[(size_t)wid * DD + lane], acc);
  R.out[(size_t)wid * DD + lane] = num / (wsum + w2v);
}

// ---------------- semantic attention: per-block partial sums, both sides ----------------
// Each block: 64 nodes, one side (blockIdx.y). Writes psums[(side*gridX+bx)*2 + m].
__global__ __launch_bounds__(256) void sem_kernel(
    const float* __restrict__ eA0, const float* __restrict__ eA1,
    const float* __restrict__ eP0, const float* __restrict__ eP1,
    const float* __restrict__ Wa, const float* __restrict__ ba, const float* __restrict__ qa,
    const float* __restrict__ Wp, const float* __restrict__ bp, const float* __restrict__ qp,
    float* __restrict__ psums)
{
  int side = blockIdx.y;
  const float* e0 = side ? eP0 : eA0;
  const float* e1 = side ? eP1 : eA1;
  const float* W = side ? Wp : Wa;
  const float* b = side ? bp : ba;
  const float* q = side ? qp : qa;

  __shared__ float Ws[DD * NSEM];
  __shared__ float zs[2][2][DD];
  __shared__ float red0[256], red1[256];
  int tid = threadIdx.x;
  {
    const float4* W4 = (const float4*)W;
    float4* Ws4 = (float4*)Ws;
    #pragma unroll
    for (int j = 0; j < 8; ++j) Ws4[tid + j * 256] = W4[tid + j * 256];
  }
  int slot = tid >> 7;
  int k = tid & 127;
  float bk = b[k], qk = q[k];
  int base = blockIdx.x * 64;
  float sum0 = 0.f, sum1 = 0.f;
  for (int it = 0; it < 32; ++it) {
    {
      int nslot = tid >> 7, m = (tid >> 6) & 1, d = tid & 63;
      int node = base + it * 2 + nslot;
      zs[nslot][m][d] = (m == 0 ? e0 : e1)[(size_t)node * DD + d];
    }
    __syncthreads();
    float acc0 = bk, acc1 = bk;
    #pragma unroll
    for (int d = 0; d < DD; ++d) {
      float w = Ws[d * NSEM + k];
      acc0 = fmaf(zs[slot][0][d], w, acc0);
      acc1 = fmaf(zs[slot][1][d], w, acc1);
    }
    sum0 += tanh_fast(acc0) * qk;
    sum1 += tanh_fast(acc1) * qk;
    __syncthreads();
  }
  red0[tid] = sum0;
  red1[tid] = sum1;
  __syncthreads();
  for (int off = 128; off; off >>= 1) {
    if (tid < off) { red0[tid] += red0[tid + off]; red1[tid] += red1[tid + off]; }
    __syncthreads();
  }
  if (tid == 0) {
    int idx = (side * gridDim.x + blockIdx.x) * 2;
    psums[idx + 0] = red0[0];
    psums[idx + 1] = red1[0];
  }
}

// both betas in one tiny kernel: beta[0..1]=A side, beta[2..3]=P side
__global__ __launch_bounds__(256) void beta_kernel(const float* __restrict__ psums,
    float* __restrict__ beta, int nblk, float invn)
{
  __shared__ float s[4][256];
  int t = threadIdx.x;
  float a0 = 0.f, a1 = 0.f, p0 = 0.f, p1 = 0.f;
  for (int i = t; i < nblk; i += 256) {
    a0 += psums[i * 2];
    a1 += psums[i * 2 + 1];
    p0 += psums[(nblk + i) * 2];
    p1 += psums[(nblk + i) * 2 + 1];
  }
  s[0][t] = a0; s[1][t] = a1; s[2][t] = p0; s[3][t] = p1;
  __syncthreads();
  for (int off = 128; off; off >>= 1) {
    if (t < off) {
      s[0][t] += s[0][t + off]; s[1][t] += s[1][t + off];
      s[2][t] += s[2][t + off]; s[3][t] += s[3][t + off];
    }
    __syncthreads();
  }
  if (t == 0) {
    float m0 = s[0][0] * invn, m1 = s[1][0] * invn;
    float mx = fmaxf(m0, m1);
    float x0 = __expf(m0 - mx), x1 = __expf(m1 - mx);
    float inv = 1.f / (x0 + x1);
    beta[0] = x0 * inv; beta[1] = x1 * inv;
    m0 = s[2][0] * invn; m1 = s[3][0] * invn;
    mx = fmaxf(m0, m1);
    x0 = __expf(m0 - mx); x1 = __expf(m1 - mx);
    inv = 1.f / (x0 + x1);
    beta[2] = x0 * inv; beta[3] = x1 * inv;
  }
}

// combine both sides (float4), ELU, in-place h update
__global__ void combine2_kernel(const float4* __restrict__ eA0, const float4* __restrict__ eA1,
    const float4* __restrict__ eP0, const float4* __restrict__ eP1,
    const float* __restrict__ beta, float4* __restrict__ hA, float4* __restrict__ hP,
    int nvec)
{
  int side = blockIdx.y;
  int i = blockIdx.x * 256 + threadIdx.x;
  if (i >= nvec) return;
  float b0 = beta[side * 2], b1 = beta[side * 2 + 1];
  float4 v0 = (side ? eP0 : eA0)[i];
  float4 v1 = (side ? eP1 : eA1)[i];
  float4 r;
  float t;
  t = b0 * v0.x + b1 * v1.x; r.x = t > 0.f ? t : (__expf(t) - 1.f);
  t = b0 * v0.y + b1 * v1.y; r.y = t > 0.f ? t : (__expf(t) - 1.f);
  t = b0 * v0.z + b1 * v1.z; r.z = t > 0.f ? t : (__expf(t) - 1.f);
  t = b0 * v0.w + b1 * v1.w; r.w = t > 0.f ? t : (__expf(t) - 1.f);
  (side ? hP : hA)[i] = r;
}

// ---------------- final projection [40000,64]@[64,4] + b2 ----------------
__global__ void final_kernel(const float* __restrict__ hA, const float* __restrict__ W2,
    const float* __restrict__ b2, float* __restrict__ out, int n)
{
  int j = blockIdx.x * blockDim.x + threadIdx.x;
  if (j >= n) return;
  float acc0 = b2[0], acc1 = b2[1], acc2 = b2[2], acc3 = b2[3];
  const float4* hrow = (const float4*)(hA + (size_t)j * DD);
  #pragma unroll
  for (int d4 = 0; d4 < 16; ++d4) {
    float4 v = hrow[d4];
    #pragma unroll
    for (int c = 0; c < 4; ++c) {
      int d = d4 * 4 + c;
      float vv = (&v.x)[c];
      acc0 = fmaf(vv, W2[d * 4 + 0], acc0);
      acc1 = fmaf(vv, W2[d * 4 + 1], acc1);
      acc2 = fmaf(vv, W2[d * 4 + 2], acc2);
      acc3 = fmaf(vv, W2[d * 4 + 3], acc3);
    }
  }
  float4 o = make_float4(acc0, acc1, acc2, acc3);
  ((float4*)out)[j] = o;
}

extern "C" void kernel_launch(void* const* d_in, const int* in_sizes, int n_in,
                              void* d_out, int out_size, void* d_ws, size_t ws_size,
                              hipStream_t stream)
{
  const float* x_author = (const float*)d_in[0];
  const float* x_paper  = (const float*)d_in[1];
  const float* W1_a = (const float*)d_in[2];
  const float* b1_a = (const float*)d_in[3];
  const float* W1_p = (const float*)d_in[4];
  const float* b1_p = (const float*)d_in[5];
  const float* a1_ap = (const float*)d_in[6];
  const float* a2_ap = (const float*)d_in[7];
  const float* a1_aa = (const float*)d_in[8];
  const float* a2_aa = (const float*)d_in[9];
  const float* a1_pa = (const float*)d_in[10];
  const float* a2_pa = (const float*)d_in[11];
  const float* a1_pp = (const float*)d_in[12];
  const float* a2_pp = (const float*)d_in[13];
  const float* semW_a = (const float*)d_in[14];
  const float* semb_a = (const float*)d_in[15];
  const float* semq_a = (const float*)d_in[16];
  const float* semW_p = (const float*)d_in[17];
  const float* semb_p = (const float*)d_in[18];
  const float* semq_p = (const float*)d_in[19];
  const float* W2 = (const float*)d_in[20];
  const float* b2 = (const float*)d_in[21];
  const int* ei[4] = {(const int*)d_in[22], (const int*)d_in[23],
                      (const int*)d_in[24], (const int*)d_in[25]};

  // ---- workspace carve ----
  char* w = (char*)d_ws;
  auto alloc = [&](size_t bytes) -> void* {
    void* p = (void*)w;
    w += (bytes + 255) & ~(size_t)255;
    return p;
  };
  const size_t matB = (size_t)NN * DD * sizeof(float);
  float* xA  = (float*)alloc(matB);
  float* xP  = (float*)alloc(matB);
  float* hA  = (float*)alloc(matB);
  float* hP  = (float*)alloc(matB);
  float* eA0 = (float*)alloc(matB);
  float* eA1 = (float*)alloc(matB);
  float* eP0 = (float*)alloc(matB);
  float* eP1 = (float*)alloc(matB);
  int* rowptr[4]; int* tsorted[4];
  for (int r = 0; r < 4; ++r) {
    rowptr[r]  = (int*)alloc((NN + 1) * sizeof(int));
    tsorted[r] = (int*)alloc((size_t)EE * sizeof(int));
  }
  int* counts = (int*)alloc((size_t)4 * NN * sizeof(int));
  int* cursor = (int*)alloc((size_t)4 * NN * sizeof(int));
  float* x1b[4], *w2b[4], *h1b[4];
  for (int r = 0; r < 4; ++r) {
    x1b[r] = (float*)alloc(NN * sizeof(float));
    w2b[r] = (float*)alloc(NN * sizeof(float));
    h1b[r] = (float*)alloc(NN * sizeof(float));
  }
  float* psums = (float*)alloc((size_t)2 * 625 * 2 * sizeof(float));
  float* betab = (float*)alloc(64);

  // ---- projections ----
  proj_gemm_relu<<<NN / PBM, 512, 0, stream>>>(x_author, W1_a, b1_a, xA, NN, 334);
  proj_gemm_relu<<<NN / PBM, 512, 0, stream>>>(x_paper,  W1_p, b1_p, xP, NN, 512);

  // ---- CSR build (4 relations, 4 dispatches) ----
  const int EB = (EE + 255) / 256;
  zero_i32<<<(4 * NN + 255) / 256, 256, 0, stream>>>(counts, 4 * NN);
  hist4_kernel<<<dim3(EB, 4), 256, 0, stream>>>(ei[0], ei[1], ei[2], ei[3], counts, EE, NN);
  scan4_kernel<<<4, 1024, 0, stream>>>(counts, rowptr[0], rowptr[1], rowptr[2], rowptr[3],
                                       cursor, NN);
  scatter4_kernel<<<dim3(EB, 4), 256, 0, stream>>>(ei[0], ei[1], ei[2], ei[3], cursor,
      tsorted[0], tsorted[1], tsorted[2], tsorted[3], EE, NN);

  // ---- hop loop ----
  const int AGG_GRID = (NN * 64) / 256;
  const int CVEC = NN * DD / 4;
  for (int i = 0; i < NHOP; ++i) {
    const float* hAc = (i == 0) ? xA : hA;
    const float* hPc = (i == 0) ? xP : hP;

    dots_kernel<<<(NN + 255) / 256, 256, 0, stream>>>(
        xA, xP, hAc, hPc,
        a1_ap + i * DD, a2_ap + i * DD, a1_aa + i * DD, a2_aa + i * DD,
        a1_pa + i * DD, a2_pa + i * DD, a1_pp + i * DD, a2_pp + i * DD,
        x1b[0], w2b[0], h1b[0], x1b[1], w2b[1], h1b[1],
        x1b[2], w2b[2], h1b[2], x1b[3], w2b[3], h1b[3], NN);

    AggRel r0 = {xA, hPc, x1b[0], w2b[0], h1b[0], rowptr[0], tsorted[0], eA0};
    AggRel r1 = {xA, hAc, x1b[1], w2b[1], h1b[1], rowptr[1], tsorted[1], eA1};
    AggRel r2 = {xP, hAc, x1b[2], w2b[2], h1b[2], rowptr[2], tsorted[2], eP0};
    AggRel r3 = {xP, hPc, x1b[3], w2b[3], h1b[3], rowptr[3], tsorted[3], eP1};
    agg4_kernel<<<dim3(AGG_GRID, 4), 256, 0, stream>>>(r0, r1, r2, r3, NN);

    sem_kernel<<<dim3(NN / 64, 2), 256, 0, stream>>>(
        eA0, eA1, eP0, eP1,
        semW_a + (size_t)i * DD * NSEM, semb_a + i * NSEM, semq_a + i * NSEM,
        semW_p + (size_t)i * DD * NSEM, semb_p + i * NSEM, semq_p + i * NSEM,
        psums);
    beta_kernel<<<1, 256, 0, stream>>>(psums, betab, NN / 64, 1.f / NN);
    combine2_kernel<<<dim3((CVEC + 255) / 256, 2), 256, 0, stream>>>(
        (const float4*)eA0, (const float4*)eA1, (const float4*)eP0, (const float4*)eP1,
        betab, (float4*)hA, (float4*)hP, CVEC);
  }

  final_kernel<<<(NN + 255) / 256, 256, 0, stream>>>(hA, W2, b2, (float*)d_out, NN);
}

// Round 3
// 1669.280 us; speedup vs baseline: 2.0403x; 1.1111x over previous
//
#include <hip/hip_runtime.h>

#define NN 40000
#define DD 64
#define EE 800000
#define NHOP 5
#define NSEM 128
#define NBK 625          // NN/64 buckets for binned scatter
#define BINCH 8192       // edges per binA block

__device__ __forceinline__ float leaky02(float v) { return v > 0.f ? v : 0.2f * v; }
__device__ __forceinline__ float tanh_fast(float x) {
  return 1.f - 2.f / (__expf(2.f * x) + 1.f);
}
__device__ __forceinline__ float wred(float x) {
  #pragma unroll
  for (int m = 1; m < 64; m <<= 1) x += __shfl_xor(x, m);
  return x;
}

// ---------------- zero kernel ----------------
__global__ void zero_i32(int* __restrict__ p, int n) {
  int i = blockIdx.x * blockDim.x + threadIdx.x;
  if (i < n) p[i] = 0;
}

// ---------------- projection GEMM + bias + relu ----------------
#define PBM 64
#define PBK 64
__global__ __launch_bounds__(512) void proj_gemm_relu(
    const float* __restrict__ X, const float* __restrict__ W,
    const float* __restrict__ bias, float* __restrict__ out, int n, int K)
{
  __shared__ float As[PBM][PBK + 1];
  __shared__ float Bs[PBK][DD];
  int tid = threadIdx.x;
  int tx = tid & 15;
  int ty = tid >> 4;
  int row0 = blockIdx.x * PBM;
  float acc[2][4] = {{0.f}};
  int nk = (K + PBK - 1) / PBK;
  for (int kt = 0; kt < nk; ++kt) {
    int k0 = kt * PBK;
    #pragma unroll
    for (int j = 0; j < 8; ++j) {
      int idx = tid + j * 512;
      int r = idx >> 6, c = idx & 63;
      int gk = k0 + c;
      As[r][c] = (gk < K) ? X[(size_t)(row0 + r) * K + gk] : 0.f;
    }
    #pragma unroll
    for (int j = 0; j < 2; ++j) {
      int idx = tid + j * 512;
      int r = idx >> 4, c4 = idx & 15;
      int gk = k0 + r;
      float4 v = (gk < K) ? ((const float4*)(W + (size_t)gk * DD))[c4]
                          : make_float4(0.f, 0.f, 0.f, 0.f);
      ((float4*)&Bs[r][0])[c4] = v;
    }
    __syncthreads();
    #pragma unroll 8
    for (int kk = 0; kk < PBK; ++kk) {
      float a0 = As[ty * 2][kk];
      float a1 = As[ty * 2 + 1][kk];
      float4 bv = ((float4*)&Bs[kk][0])[tx];
      acc[0][0] = fmaf(a0, bv.x, acc[0][0]);
      acc[0][1] = fmaf(a0, bv.y, acc[0][1]);
      acc[0][2] = fmaf(a0, bv.z, acc[0][2]);
      acc[0][3] = fmaf(a0, bv.w, acc[0][3]);
      acc[1][0] = fmaf(a1, bv.x, acc[1][0]);
      acc[1][1] = fmaf(a1, bv.y, acc[1][1]);
      acc[1][2] = fmaf(a1, bv.z, acc[1][2]);
      acc[1][3] = fmaf(a1, bv.w, acc[1][3]);
    }
    __syncthreads();
  }
  float4 bb = ((const float4*)bias)[tx];
  #pragma unroll
  for (int i = 0; i < 2; ++i) {
    int gr = row0 + ty * 2 + i;
    float4 v;
    v.x = fmaxf(acc[i][0] + bb.x, 0.f);
    v.y = fmaxf(acc[i][1] + bb.y, 0.f);
    v.z = fmaxf(acc[i][2] + bb.z, 0.f);
    v.w = fmaxf(acc[i][3] + bb.w, 0.f);
    ((float4*)(out + (size_t)gr * DD))[tx] = v;
  }
}

// ---------------- CSR build ----------------
__global__ void hist4_kernel(const int* __restrict__ e0, const int* __restrict__ e1,
    const int* __restrict__ e2, const int* __restrict__ e3,
    int* __restrict__ counts, int e, int n)
{
  int rel = blockIdx.y;
  const int* s = rel == 0 ? e0 : rel == 1 ? e1 : rel == 2 ? e2 : e3;
  int i = blockIdx.x * blockDim.x + threadIdx.x;
  if (i < e) atomicAdd(&counts[(size_t)rel * n + s[i]], 1);
}

// rowptr per relation + bucket cursor init (bcur[rel][b] = rowptr[b*64])
__global__ __launch_bounds__(1024) void scan4_kernel(const int* __restrict__ counts,
    int* __restrict__ rp0, int* __restrict__ rp1, int* __restrict__ rp2,
    int* __restrict__ rp3, int* __restrict__ bcur, int n)
{
  int rel = blockIdx.x;
  const int* c = counts + (size_t)rel * n;
  int* rowptr = rel == 0 ? rp0 : rel == 1 ? rp1 : rel == 2 ? rp2 : rp3;
  __shared__ int tot[1024];
  int t = threadIdx.x;
  int chunk = (n + 1023) / 1024;
  int beg = t * chunk;
  int end = min(beg + chunk, n);
  int ssum = 0;
  for (int i = beg; i < end; ++i) ssum += c[i];
  tot[t] = ssum;
  __syncthreads();
  for (int off = 1; off < 1024; off <<= 1) {
    int v = (t >= off) ? tot[t - off] : 0;
    __syncthreads();
    tot[t] += v;
    __syncthreads();
  }
  int run = (t == 0) ? 0 : tot[t - 1];
  for (int i = beg; i < end; ++i) {
    rowptr[i] = run;
    run += c[i];
  }
  if (t == 1023) rowptr[n] = tot[1023];
  __syncthreads();
  for (int b = t; b < NBK; b += 1024) bcur[rel * NBK + b] = rowptr[b * 64];
}

// pass A: bin edges into 625 buckets (64 nodes each), block-claimed ranges
__global__ __launch_bounds__(256) void binA_kernel(
    const int* __restrict__ e0, const int* __restrict__ e1,
    const int* __restrict__ e2, const int* __restrict__ e3,
    int* __restrict__ bcur, int2* __restrict__ pairbuf, int e)
{
  int rel = blockIdx.y;
  const int* S = rel == 0 ? e0 : rel == 1 ? e1 : rel == 2 ? e2 : e3;
  const int* T = S + e;
  int2* pb = pairbuf + (size_t)rel * e;
  __shared__ int cnt[NBK], base[NBK], cnt2[NBK];
  int tid = threadIdx.x;
  for (int b = tid; b < NBK; b += 256) { cnt[b] = 0; cnt2[b] = 0; }
  __syncthreads();
  int e0i = blockIdx.x * BINCH;
  int ne = min(BINCH, e - e0i);
  for (int i = tid; i < ne; i += 256) atomicAdd(&cnt[S[e0i + i] >> 6], 1);
  __syncthreads();
  for (int b = tid; b < NBK; b += 256)
    base[b] = cnt[b] ? atomicAdd(&bcur[rel * NBK + b], cnt[b]) : 0;
  __syncthreads();
  for (int i = tid; i < ne; i += 256) {
    int s = S[e0i + i];
    int t = T[e0i + i];
    int b = s >> 6;
    int off = atomicAdd(&cnt2[b], 1);
    pb[base[b] + off] = make_int2(s, t);
  }
}

// pass B: one block per bucket; exclusive contiguous output region
__global__ __launch_bounds__(256) void binB_kernel(
    const int2* __restrict__ pairbuf,
    const int* __restrict__ rp0, const int* __restrict__ rp1,
    const int* __restrict__ rp2, const int* __restrict__ rp3,
    int* __restrict__ ts0, int* __restrict__ ts1, int* __restrict__ ts2,
    int* __restrict__ ts3, int e)
{
  int rel = blockIdx.y;
  const int* rowptr = rel == 0 ? rp0 : rel == 1 ? rp1 : rel == 2 ? rp2 : rp3;
  int* ts = rel == 0 ? ts0 : rel == 1 ? ts1 : rel == 2 ? ts2 : ts3;
  const int2* pb = pairbuf + (size_t)rel * e;
  __shared__ int cur[64];
  int tid = threadIdx.x;
  int node0 = blockIdx.x * 64;
  if (tid < 64) cur[tid] = rowptr[node0 + tid];
  __syncthreads();
  int regbeg = rowptr[node0];
  int regend = rowptr[node0 + 64];
  for (int i = regbeg + tid; i < regend; i += 256) {
    int2 p = pb[i];
    int pos = atomicAdd(&cur[p.x - node0], 1);
    ts[pos] = p.y;
  }
}

// ---------------- upfront: x1/w2 for all hops + hop-0 h1 ----------------
// grid (NN/16, 2 sides), block 1024 (16 rows)
__global__ __launch_bounds__(1024) void precompute_xw(
    const float* __restrict__ xA, const float* __restrict__ xP,
    const float* __restrict__ a1_ap, const float* __restrict__ a2_ap,
    const float* __restrict__ a1_aa, const float* __restrict__ a2_aa,
    const float* __restrict__ a1_pa, const float* __restrict__ a2_pa,
    const float* __restrict__ a1_pp, const float* __restrict__ a2_pp,
    float* __restrict__ x1all, float* __restrict__ w2all,
    float* __restrict__ h1_ap, float* __restrict__ h1_aa,
    float* __restrict__ h1_pa, float* __restrict__ h1_pp)
{
  __shared__ float Ls[8][NHOP * DD];
  int tid = threadIdx.x;
  {
    const float* srcs[8] = {a1_ap, a2_ap, a1_aa, a2_aa, a1_pa, a2_pa, a1_pp, a2_pp};
    for (int i = tid; i < 8 * NHOP * DD; i += 1024)
      Ls[i / (NHOP * DD)][i % (NHOP * DD)] = srcs[i / (NHOP * DD)][i % (NHOP * DD)];
  }
  __syncthreads();
  int side = blockIdx.y;
  int wid = tid >> 6, lane = tid & 63;
  int row = blockIdx.x * 16 + wid;
  float v = (side ? xP : xA)[(size_t)row * DD + lane];
  int r0 = side ? 4 : 0;  // Ls base index for this side's a-vectors
  int relA = side ? 2 : 0;
  #pragma unroll
  for (int i = 0; i < NHOP; ++i) {
    float r1 = wred(v * Ls[r0 + 0][i * DD + lane]);
    float r2 = wred(v * Ls[r0 + 1][i * DD + lane]);
    float r3 = wred(v * Ls[r0 + 2][i * DD + lane]);
    float r4 = wred(v * Ls[r0 + 3][i * DD + lane]);
    if (lane == 0) {
      x1all[((size_t)(relA + 0) * NHOP + i) * NN + row] = r1;
      w2all[((size_t)(relA + 0) * NHOP + i) * NN + row] = __expf(leaky02(r1 + r2));
      x1all[((size_t)(relA + 1) * NHOP + i) * NN + row] = r3;
      w2all[((size_t)(relA + 1) * NHOP + i) * NN + row] = __expf(leaky02(r3 + r4));
      if (i == 0) (side ? h1_pp : h1_aa)[row] = r4;
    }
    if (i == 0) {
      // side A needs h1_pa = xA.a2_pa[0] (Ls[5]); side P needs h1_ap = xP.a2_ap[0] (Ls[1])
      float r5 = wred(v * Ls[side ? 1 : 5][lane]);
      if (lane == 0) (side ? h1_ap : h1_pa)[row] = r5;
    }
  }
}

// ---------------- fused edge aggregation: 4 relations, one wave per node ----------------
struct AggRel {
  const float* x; const float* h; const float* x1; const float* w2; const float* h1;
  const int* rowptr; const int* tsorted; float* out;
};

__global__ __launch_bounds__(256) void agg4_kernel(AggRel r0, AggRel r1, AggRel r2,
                                                   AggRel r3, int n)
{
  AggRel R;
  switch (blockIdx.y) {
    case 0: R = r0; break;
    case 1: R = r1; break;
    case 2: R = r2; break;
    default: R = r3; break;
  }
  int wid = (blockIdx.x * blockDim.x + threadIdx.x) >> 6;
  int lane = threadIdx.x & 63;
  if (wid >= n) return;
  int beg = R.rowptr[wid], end = R.rowptr[wid + 1];
  float x1i = R.x1[wid];
  float acc = 0.f, wsum = 0.f;
  int e = beg;
  for (; e + 4 <= end; e += 4) {
    int t0 = R.tsorted[e], t1 = R.tsorted[e + 1];
    int t2 = R.tsorted[e + 2], t3 = R.tsorted[e + 3];
    float s0 = R.h1[t0], s1 = R.h1[t1], s2 = R.h1[t2], s3 = R.h1[t3];
    float v0 = R.h[(size_t)t0 * DD + lane];
    float v1 = R.h[(size_t)t1 * DD + lane];
    float v2 = R.h[(size_t)t2 * DD + lane];
    float v3 = R.h[(size_t)t3 * DD + lane];
    float w0 = __expf(leaky02(x1i + s0));
    float w1 = __expf(leaky02(x1i + s1));
    float w2_ = __expf(leaky02(x1i + s2));
    float w3 = __expf(leaky02(x1i + s3));
    wsum += (w0 + w1) + (w2_ + w3);
    acc = fmaf(w0, v0, acc);
    acc = fmaf(w1, v1, acc);
    acc = fmaf(w2_, v2, acc);
    acc = fmaf(w3, v3, acc);
  }
  for (; e < end; ++e) {
    int t = R.tsorted[e];
    float w = __expf(leaky02(x1i + R.h1[t]));
    wsum += w;
    acc = fmaf(w, R.h[(size_t)t * DD + lane], acc);
  }
  float w2v = R.w2[wid];
  float num = fmaf(w2v, R.x[(size_t)wid * DD + lane], acc);
  R.out[(size_t)wid * DD + lane] = num / (wsum + w2v);
}

// ---------------- semantic attention partial sums (8 nodes/iter) ----------------
__global__ __launch_bounds__(256) void sem_kernel(
    const float* __restrict__ eA0, const float* __restrict__ eA1,
    const float* __restrict__ eP0, const float* __restrict__ eP1,
    const float* __restrict__ Wa, const float* __restrict__ ba, const float* __restrict__ qa,
    const float* __restrict__ Wp, const float* __restrict__ bp, const float* __restrict__ qp,
    float* __restrict__ psums)
{
  int side = blockIdx.y;
  const float* e0 = side ? eP0 : eA0;
  const float* e1 = side ? eP1 : eA1;
  const float* W = side ? Wp : Wa;
  const float* b = side ? bp : ba;
  const float* q = side ? qp : qa;

  __shared__ float Ws[DD * NSEM];
  __shared__ float zs[8][2][DD];
  __shared__ float red0[256], red1[256];
  int tid = threadIdx.x;
  {
    const float4* W4 = (const float4*)W;
    float4* Ws4 = (float4*)Ws;
    #pragma unroll
    for (int j = 0; j < 8; ++j) Ws4[tid + j * 256] = W4[tid + j * 256];
  }
  int slot = tid >> 7;
  int k = tid & 127;
  float bk = b[k], qk = q[k];
  int base = blockIdx.x * 64;
  float sum0 = 0.f, sum1 = 0.f;
  for (int it = 0; it < 8; ++it) {
    #pragma unroll
    for (int j = 0; j < 4; ++j) {
      int idx = tid + j * 256;
      int nn = idx >> 7, m = (idx >> 6) & 1, d = idx & 63;
      int node = base + it * 8 + nn;
      zs[nn][m][d] = (m ? e1 : e0)[(size_t)node * DD + d];
    }
    __syncthreads();
    float acc[4][2];
    #pragma unroll
    for (int nn = 0; nn < 4; ++nn) { acc[nn][0] = bk; acc[nn][1] = bk; }
    #pragma unroll 8
    for (int d = 0; d < DD; ++d) {
      float w = Ws[d * NSEM + k];
      #pragma unroll
      for (int nn = 0; nn < 4; ++nn) {
        acc[nn][0] = fmaf(zs[slot * 4 + nn][0][d], w, acc[nn][0]);
        acc[nn][1] = fmaf(zs[slot * 4 + nn][1][d], w, acc[nn][1]);
      }
    }
    #pragma unroll
    for (int nn = 0; nn < 4; ++nn) {
      sum0 += tanh_fast(acc[nn][0]) * qk;
      sum1 += tanh_fast(acc[nn][1]) * qk;
    }
    __syncthreads();
  }
  red0[tid] = sum0;
  red1[tid] = sum1;
  __syncthreads();
  for (int off = 128; off; off >>= 1) {
    if (tid < off) { red0[tid] += red0[tid + off]; red1[tid] += red1[tid + off]; }
    __syncthreads();
  }
  if (tid == 0) {
    int idx = (side * gridDim.x + blockIdx.x) * 2;
    psums[idx + 0] = red0[0];
    psums[idx + 1] = red1[0];
  }
}

__global__ __launch_bounds__(256) void beta_kernel(const float* __restrict__ psums,
    float* __restrict__ beta, int nblk, float invn)
{
  __shared__ float s[4][256];
  int t = threadIdx.x;
  float a0 = 0.f, a1 = 0.f, p0 = 0.f, p1 = 0.f;
  for (int i = t; i < nblk; i += 256) {
    a0 += psums[i * 2];
    a1 += psums[i * 2 + 1];
    p0 += psums[(nblk + i) * 2];
    p1 += psums[(nblk + i) * 2 + 1];
  }
  s[0][t] = a0; s[1][t] = a1; s[2][t] = p0; s[3][t] = p1;
  __syncthreads();
  for (int off = 128; off; off >>= 1) {
    if (t < off) {
      s[0][t] += s[0][t + off]; s[1][t] += s[1][t + off];
      s[2][t] += s[2][t + off]; s[3][t] += s[3][t + off];
    }
    __syncthreads();
  }
  if (t == 0) {
    float m0 = s[0][0] * invn, m1 = s[1][0] * invn;
    float mx = fmaxf(m0, m1);
    float x0 = __expf(m0 - mx), x1 = __expf(m1 - mx);
    float inv = 1.f / (x0 + x1);
    beta[0] = x0 * inv; beta[1] = x1 * inv;
    m0 = s[2][0] * invn; m1 = s[3][0] * invn;
    mx = fmaxf(m0, m1);
    x0 = __expf(m0 - mx); x1 = __expf(m1 - mx);
    inv = 1.f / (x0 + x1);
    beta[2] = x0 * inv; beta[3] = x1 * inv;
  }
}

// ---------------- combine + ELU + fused next-hop h1 (wave per row) ----------------
__global__ __launch_bounds__(256) void combine_h1_kernel(
    const float* __restrict__ eA0, const float* __restrict__ eA1,
    const float* __restrict__ eP0, const float* __restrict__ eP1,
    const float* __restrict__ beta, float* __restrict__ hA, float* __restrict__ hP,
    const float* __restrict__ a2_aa_n, const float* __restrict__ a2_pa_n,
    const float* __restrict__ a2_ap_n, const float* __restrict__ a2_pp_n,
    float* __restrict__ h1_ap, float* __restrict__ h1_aa,
    float* __restrict__ h1_pa, float* __restrict__ h1_pp, int has_next)
{
  int side = blockIdx.y;
  int wid = threadIdx.x >> 6, lane = threadIdx.x & 63;
  int row = blockIdx.x * 4 + wid;
  const float* e0 = side ? eP0 : eA0;
  const float* e1 = side ? eP1 : eA1;
  float b0 = beta[side * 2], b1 = beta[side * 2 + 1];
  float v0 = e0[(size_t)row * DD + lane];
  float v1 = e1[(size_t)row * DD + lane];
  float t = b0 * v0 + b1 * v1;
  float v = t > 0.f ? t : (__expf(t) - 1.f);
  (side ? hP : hA)[(size_t)row * DD + lane] = v;
  if (has_next) {
    const float* ax = side ? a2_ap_n : a2_aa_n;
    const float* ay = side ? a2_pp_n : a2_pa_n;
    float rx = wred(v * ax[lane]);
    float ry = wred(v * ay[lane]);
    if (lane == 0) {
      if (side) { h1_ap[row] = rx; h1_pp[row] = ry; }
      else      { h1_aa[row] = rx; h1_pa[row] = ry; }
    }
  }
}

// ---------------- final projection ----------------
__global__ void final_kernel(const float* __restrict__ hA, const float* __restrict__ W2,
    const float* __restrict__ b2, float* __restrict__ out, int n)
{
  int j = blockIdx.x * blockDim.x + threadIdx.x;
  if (j >= n) return;
  float acc0 = b2[0], acc1 = b2[1], acc2 = b2[2], acc3 = b2[3];
  const float4* hrow = (const float4*)(hA + (size_t)j * DD);
  #pragma unroll
  for (int d4 = 0; d4 < 16; ++d4) {
    float4 v = hrow[d4];
    #pragma unroll
    for (int c = 0; c < 4; ++c) {
      int d = d4 * 4 + c;
      float vv = (&v.x)[c];
      acc0 = fmaf(vv, W2[d * 4 + 0], acc0);
      acc1 = fmaf(vv, W2[d * 4 + 1], acc1);
      acc2 = fmaf(vv, W2[d * 4 + 2], acc2);
      acc3 = fmaf(vv, W2[d * 4 + 3], acc3);
    }
  }
  ((float4*)out)[j] = make_float4(acc0, acc1, acc2, acc3);
}

extern "C" void kernel_launch(void* const* d_in, const int* in_sizes, int n_in,
                              void* d_out, int out_size, void* d_ws, size_t ws_size,
                              hipStream_t stream)
{
  const float* x_author = (const float*)d_in[0];
  const float* x_paper  = (const float*)d_in[1];
  const float* W1_a = (const float*)d_in[2];
  const float* b1_a = (const float*)d_in[3];
  const float* W1_p = (const float*)d_in[4];
  const float* b1_p = (const float*)d_in[5];
  const float* a1_ap = (const float*)d_in[6];
  const float* a2_ap = (const float*)d_in[7];
  const float* a1_aa = (const float*)d_in[8];
  const float* a2_aa = (const float*)d_in[9];
  const float* a1_pa = (const float*)d_in[10];
  const float* a2_pa = (const float*)d_in[11];
  const float* a1_pp = (const float*)d_in[12];
  const float* a2_pp = (const float*)d_in[13];
  const float* semW_a = (const float*)d_in[14];
  const float* semb_a = (const float*)d_in[15];
  const float* semq_a = (const float*)d_in[16];
  const float* semW_p = (const float*)d_in[17];
  const float* semb_p = (const float*)d_in[18];
  const float* semq_p = (const float*)d_in[19];
  const float* W2 = (const float*)d_in[20];
  const float* b2 = (const float*)d_in[21];
  const int* ei[4] = {(const int*)d_in[22], (const int*)d_in[23],
                      (const int*)d_in[24], (const int*)d_in[25]};

  // ---- workspace carve ----
  char* w = (char*)d_ws;
  auto alloc = [&](size_t bytes) -> void* {
    void* p = (void*)w;
    w += (bytes + 255) & ~(size_t)255;
    return p;
  };
  const size_t matB = (size_t)NN * DD * sizeof(float);
  float* xA  = (float*)alloc(matB);
  float* xP  = (float*)alloc(matB);
  float* hA  = (float*)alloc(matB);
  float* hP  = (float*)alloc(matB);
  float* eA0 = (float*)alloc(matB);
  float* eA1 = (float*)alloc(matB);
  float* eP0 = (float*)alloc(matB);
  float* eP1 = (float*)alloc(matB);
  // pairbuf (4*E int2 = 25.6 MB) aliases eA0.. (CSR build precedes e-buffer writes)
  int2* pairbuf = (int2*)eA0;
  int* rowptr[4]; int* tsorted[4];
  for (int r = 0; r < 4; ++r) {
    rowptr[r]  = (int*)alloc((NN + 1) * sizeof(int));
    tsorted[r] = (int*)alloc((size_t)EE * sizeof(int));
  }
  int* counts = (int*)alloc((size_t)4 * NN * sizeof(int));
  int* bcur   = (int*)alloc((size_t)4 * NBK * sizeof(int));
  float* x1all = (float*)alloc((size_t)4 * NHOP * NN * sizeof(float));
  float* w2all = (float*)alloc((size_t)4 * NHOP * NN * sizeof(float));
  float* h1b[4];
  for (int r = 0; r < 4; ++r) h1b[r] = (float*)alloc(NN * sizeof(float));
  float* psums = (float*)alloc((size_t)2 * NBK * 2 * sizeof(float));
  float* betab = (float*)alloc(64);

  // ---- projections ----
  proj_gemm_relu<<<NN / PBM, 512, 0, stream>>>(x_author, W1_a, b1_a, xA, NN, 334);
  proj_gemm_relu<<<NN / PBM, 512, 0, stream>>>(x_paper,  W1_p, b1_p, xP, NN, 512);

  // ---- CSR build ----
  const int EB = (EE + 255) / 256;
  zero_i32<<<(4 * NN + 255) / 256, 256, 0, stream>>>(counts, 4 * NN);
  hist4_kernel<<<dim3(EB, 4), 256, 0, stream>>>(ei[0], ei[1], ei[2], ei[3], counts, EE, NN);
  scan4_kernel<<<4, 1024, 0, stream>>>(counts, rowptr[0], rowptr[1], rowptr[2], rowptr[3],
                                       bcur, NN);
  binA_kernel<<<dim3((EE + BINCH - 1) / BINCH, 4), 256, 0, stream>>>(
      ei[0], ei[1], ei[2], ei[3], bcur, pairbuf, EE);
  binB_kernel<<<dim3(NBK, 4), 256, 0, stream>>>(pairbuf,
      rowptr[0], rowptr[1], rowptr[2], rowptr[3],
      tsorted[0], tsorted[1], tsorted[2], tsorted[3], EE);

  // ---- upfront x1/w2 (all hops) + hop-0 h1 ----
  precompute_xw<<<dim3(NN / 16, 2), 1024, 0, stream>>>(
      xA, xP, a1_ap, a2_ap, a1_aa, a2_aa, a1_pa, a2_pa, a1_pp, a2_pp,
      x1all, w2all, h1b[0], h1b[1], h1b[2], h1b[3]);

  // ---- hop loop ----
  const int AGG_GRID = (NN * 64) / 256;
  for (int i = 0; i < NHOP; ++i) {
    const float* hAc = (i == 0) ? xA : hA;
    const float* hPc = (i == 0) ? xP : hP;
    #define X1(r) (x1all + ((size_t)(r) * NHOP + i) * NN)
    #define W2P(r) (w2all + ((size_t)(r) * NHOP + i) * NN)
    AggRel r0 = {xA, hPc, X1(0), W2P(0), h1b[0], rowptr[0], tsorted[0], eA0};
    AggRel r1 = {xA, hAc, X1(1), W2P(1), h1b[1], rowptr[1], tsorted[1], eA1};
    AggRel r2 = {xP, hAc, X1(2), W2P(2), h1b[2], rowptr[2], tsorted[2], eP0};
    AggRel r3 = {xP, hPc, X1(3), W2P(3), h1b[3], rowptr[3], tsorted[3], eP1};
    agg4_kernel<<<dim3(AGG_GRID, 4), 256, 0, stream>>>(r0, r1, r2, r3, NN);

    sem_kernel<<<dim3(NN / 64, 2), 256, 0, stream>>>(
        eA0, eA1, eP0, eP1,
        semW_a + (size_t)i * DD * NSEM, semb_a + i * NSEM, semq_a + i * NSEM,
        semW_p + (size_t)i * DD * NSEM, semb_p + i * NSEM, semq_p + i * NSEM,
        psums);
    beta_kernel<<<1, 256, 0, stream>>>(psums, betab, NN / 64, 1.f / NN);

    int inext = (i + 1 < NHOP) ? (i + 1) : i;
    combine_h1_kernel<<<dim3(NN / 4, 2), 256, 0, stream>>>(
        eA0, eA1, eP0, eP1, betab, hA, hP,
        a2_aa + inext * DD, a2_pa + inext * DD, a2_ap + inext * DD, a2_pp + inext * DD,
        h1b[0], h1b[1], h1b[2], h1b[3], (i + 1 < NHOP) ? 1 : 0);
  }

  final_kernel<<<(NN + 255) / 256, 256, 0, stream>>>(hA, W2, b2, (float*)d_out, NN);
}

// Round 4
// 1524.198 us; speedup vs baseline: 2.2345x; 1.0952x over previous
//
#include <hip/hip_runtime.h>
#include <hip/hip_fp16.h>

#define NN 40000
#define DD 64
#define EE 800000
#define NHOP 5
#define NSEM 128
#define NBK 625          // NN/64 buckets for binned scatter
#define BINCH 8192       // edges per binA block

__device__ __forceinline__ float leaky02(float v) { return v > 0.f ? v : 0.2f * v; }
__device__ __forceinline__ float tanh_fast(float x) {
  return 1.f - 2.f / (__expf(2.f * x) + 1.f);
}
__device__ __forceinline__ float wred(float x) {
  #pragma unroll
  for (int m = 1; m < 64; m <<= 1) x += __shfl_xor(x, m);
  return x;
}

// ---------------- zero kernel ----------------
__global__ void zero_i32(int* __restrict__ p, int n) {
  int i = blockIdx.x * blockDim.x + threadIdx.x;
  if (i < n) p[i] = 0;
}

// ---------------- projection GEMM + bias + relu (f32 out + fp16 copy) ----------------
#define PBM 64
#define PBK 64
__global__ __launch_bounds__(512) void proj_gemm_relu(
    const float* __restrict__ X, const float* __restrict__ W,
    const float* __restrict__ bias, float* __restrict__ out,
    __half* __restrict__ out16, int n, int K)
{
  __shared__ float As[PBM][PBK + 1];
  __shared__ float Bs[PBK][DD];
  int tid = threadIdx.x;
  int tx = tid & 15;
  int ty = tid >> 4;
  int row0 = blockIdx.x * PBM;
  float acc[2][4] = {{0.f}};
  int nk = (K + PBK - 1) / PBK;
  for (int kt = 0; kt < nk; ++kt) {
    int k0 = kt * PBK;
    #pragma unroll
    for (int j = 0; j < 8; ++j) {
      int idx = tid + j * 512;
      int r = idx >> 6, c = idx & 63;
      int gk = k0 + c;
      As[r][c] = (gk < K) ? X[(size_t)(row0 + r) * K + gk] : 0.f;
    }
    #pragma unroll
    for (int j = 0; j < 2; ++j) {
      int idx = tid + j * 512;
      int r = idx >> 4, c4 = idx & 15;
      int gk = k0 + r;
      float4 v = (gk < K) ? ((const float4*)(W + (size_t)gk * DD))[c4]
                          : make_float4(0.f, 0.f, 0.f, 0.f);
      ((float4*)&Bs[r][0])[c4] = v;
    }
    __syncthreads();
    #pragma unroll 8
    for (int kk = 0; kk < PBK; ++kk) {
      float a0 = As[ty * 2][kk];
      float a1 = As[ty * 2 + 1][kk];
      float4 bv = ((float4*)&Bs[kk][0])[tx];
      acc[0][0] = fmaf(a0, bv.x, acc[0][0]);
      acc[0][1] = fmaf(a0, bv.y, acc[0][1]);
      acc[0][2] = fmaf(a0, bv.z, acc[0][2]);
      acc[0][3] = fmaf(a0, bv.w, acc[0][3]);
      acc[1][0] = fmaf(a1, bv.x, acc[1][0]);
      acc[1][1] = fmaf(a1, bv.y, acc[1][1]);
      acc[1][2] = fmaf(a1, bv.z, acc[1][2]);
      acc[1][3] = fmaf(a1, bv.w, acc[1][3]);
    }
    __syncthreads();
  }
  float4 bb = ((const float4*)bias)[tx];
  #pragma unroll
  for (int i = 0; i < 2; ++i) {
    int gr = row0 + ty * 2 + i;
    float4 v;
    v.x = fmaxf(acc[i][0] + bb.x, 0.f);
    v.y = fmaxf(acc[i][1] + bb.y, 0.f);
    v.z = fmaxf(acc[i][2] + bb.z, 0.f);
    v.w = fmaxf(acc[i][3] + bb.w, 0.f);
    ((float4*)(out + (size_t)gr * DD))[tx] = v;
    __half2 p0 = __floats2half2_rn(v.x, v.y);
    __half2 p1 = __floats2half2_rn(v.z, v.w);
    ((__half2*)(out16 + (size_t)gr * DD))[tx * 2 + 0] = p0;
    ((__half2*)(out16 + (size_t)gr * DD))[tx * 2 + 1] = p1;
  }
}

// ---------------- CSR build ----------------
__global__ void hist4_kernel(const int* __restrict__ e0, const int* __restrict__ e1,
    const int* __restrict__ e2, const int* __restrict__ e3,
    int* __restrict__ counts, int e, int n)
{
  int rel = blockIdx.y;
  const int* s = rel == 0 ? e0 : rel == 1 ? e1 : rel == 2 ? e2 : e3;
  int i = blockIdx.x * blockDim.x + threadIdx.x;
  if (i < e) atomicAdd(&counts[(size_t)rel * n + s[i]], 1);
}

__global__ __launch_bounds__(1024) void scan4_kernel(const int* __restrict__ counts,
    int* __restrict__ rp0, int* __restrict__ rp1, int* __restrict__ rp2,
    int* __restrict__ rp3, int* __restrict__ bcur, int n)
{
  int rel = blockIdx.x;
  const int* c = counts + (size_t)rel * n;
  int* rowptr = rel == 0 ? rp0 : rel == 1 ? rp1 : rel == 2 ? rp2 : rp3;
  __shared__ int tot[1024];
  int t = threadIdx.x;
  int chunk = (n + 1023) / 1024;
  int beg = t * chunk;
  int end = min(beg + chunk, n);
  int ssum = 0;
  for (int i = beg; i < end; ++i) ssum += c[i];
  tot[t] = ssum;
  __syncthreads();
  for (int off = 1; off < 1024; off <<= 1) {
    int v = (t >= off) ? tot[t - off] : 0;
    __syncthreads();
    tot[t] += v;
    __syncthreads();
  }
  int run = (t == 0) ? 0 : tot[t - 1];
  for (int i = beg; i < end; ++i) {
    rowptr[i] = run;
    run += c[i];
  }
  if (t == 1023) rowptr[n] = tot[1023];
  __syncthreads();
  for (int b = t; b < NBK; b += 1024) bcur[rel * NBK + b] = rowptr[b * 64];
}

__global__ __launch_bounds__(256) void binA_kernel(
    const int* __restrict__ e0, const int* __restrict__ e1,
    const int* __restrict__ e2, const int* __restrict__ e3,
    int* __restrict__ bcur, int2* __restrict__ pairbuf, int e)
{
  int rel = blockIdx.y;
  const int* S = rel == 0 ? e0 : rel == 1 ? e1 : rel == 2 ? e2 : e3;
  const int* T = S + e;
  int2* pb = pairbuf + (size_t)rel * e;
  __shared__ int cnt[NBK], base[NBK], cnt2[NBK];
  int tid = threadIdx.x;
  for (int b = tid; b < NBK; b += 256) { cnt[b] = 0; cnt2[b] = 0; }
  __syncthreads();
  int e0i = blockIdx.x * BINCH;
  int ne = min(BINCH, e - e0i);
  for (int i = tid; i < ne; i += 256) atomicAdd(&cnt[S[e0i + i] >> 6], 1);
  __syncthreads();
  for (int b = tid; b < NBK; b += 256)
    base[b] = cnt[b] ? atomicAdd(&bcur[rel * NBK + b], cnt[b]) : 0;
  __syncthreads();
  for (int i = tid; i < ne; i += 256) {
    int s = S[e0i + i];
    int t = T[e0i + i];
    int b = s >> 6;
    int off = atomicAdd(&cnt2[b], 1);
    pb[base[b] + off] = make_int2(s, t);
  }
}

__global__ __launch_bounds__(256) void binB_kernel(
    const int2* __restrict__ pairbuf,
    const int* __restrict__ rp0, const int* __restrict__ rp1,
    const int* __restrict__ rp2, const int* __restrict__ rp3,
    int* __restrict__ ts0, int* __restrict__ ts1, int* __restrict__ ts2,
    int* __restrict__ ts3, int e)
{
  int rel = blockIdx.y;
  const int* rowptr = rel == 0 ? rp0 : rel == 1 ? rp1 : rel == 2 ? rp2 : rp3;
  int* ts = rel == 0 ? ts0 : rel == 1 ? ts1 : rel == 2 ? ts2 : ts3;
  const int2* pb = pairbuf + (size_t)rel * e;
  __shared__ int cur[64];
  int tid = threadIdx.x;
  int node0 = blockIdx.x * 64;
  if (tid < 64) cur[tid] = rowptr[node0 + tid];
  __syncthreads();
  int regbeg = rowptr[node0];
  int regend = rowptr[node0 + 64];
  for (int i = regbeg + tid; i < regend; i += 256) {
    int2 p = pb[i];
    int pos = atomicAdd(&cur[p.x - node0], 1);
    ts[pos] = p.y;
  }
}

// ---------------- upfront: x1/w2 for all hops + hop-0 h1 ----------------
__global__ __launch_bounds__(1024) void precompute_xw(
    const float* __restrict__ xA, const float* __restrict__ xP,
    const float* __restrict__ a1_ap, const float* __restrict__ a2_ap,
    const float* __restrict__ a1_aa, const float* __restrict__ a2_aa,
    const float* __restrict__ a1_pa, const float* __restrict__ a2_pa,
    const float* __restrict__ a1_pp, const float* __restrict__ a2_pp,
    float* __restrict__ x1all, float* __restrict__ w2all,
    float* __restrict__ h1_ap, float* __restrict__ h1_aa,
    float* __restrict__ h1_pa, float* __restrict__ h1_pp)
{
  __shared__ float Ls[8][NHOP * DD];
  int tid = threadIdx.x;
  {
    const float* srcs[8] = {a1_ap, a2_ap, a1_aa, a2_aa, a1_pa, a2_pa, a1_pp, a2_pp};
    for (int i = tid; i < 8 * NHOP * DD; i += 1024)
      Ls[i / (NHOP * DD)][i % (NHOP * DD)] = srcs[i / (NHOP * DD)][i % (NHOP * DD)];
  }
  __syncthreads();
  int side = blockIdx.y;
  int wid = tid >> 6, lane = tid & 63;
  int row = blockIdx.x * 16 + wid;
  float v = (side ? xP : xA)[(size_t)row * DD + lane];
  int r0 = side ? 4 : 0;
  int relA = side ? 2 : 0;
  #pragma unroll
  for (int i = 0; i < NHOP; ++i) {
    float r1 = wred(v * Ls[r0 + 0][i * DD + lane]);
    float r2 = wred(v * Ls[r0 + 1][i * DD + lane]);
    float r3 = wred(v * Ls[r0 + 2][i * DD + lane]);
    float r4 = wred(v * Ls[r0 + 3][i * DD + lane]);
    if (lane == 0) {
      x1all[((size_t)(relA + 0) * NHOP + i) * NN + row] = r1;
      w2all[((size_t)(relA + 0) * NHOP + i) * NN + row] = __expf(leaky02(r1 + r2));
      x1all[((size_t)(relA + 1) * NHOP + i) * NN + row] = r3;
      w2all[((size_t)(relA + 1) * NHOP + i) * NN + row] = __expf(leaky02(r3 + r4));
      if (i == 0) (side ? h1_pp : h1_aa)[row] = r4;
    }
    if (i == 0) {
      float r5 = wred(v * Ls[side ? 1 : 5][lane]);
      if (lane == 0) (side ? h1_ap : h1_pa)[row] = r5;
    }
  }
}

// ---------------- fused edge aggregation: shuffle-score + fp16 gather ----------------
struct AggRel {
  const float* x; const __half* h16; const float* x1; const float* w2; const float* h1;
  const int* rowptr; const int* tsorted; float* out;
};

__global__ __launch_bounds__(256) void agg4_kernel(AggRel r0, AggRel r1, AggRel r2,
                                                   AggRel r3, int n)
{
  AggRel R;
  switch (blockIdx.y) {
    case 0: R = r0; break;
    case 1: R = r1; break;
    case 2: R = r2; break;
    default: R = r3; break;
  }
  int wid = (blockIdx.x * blockDim.x + threadIdx.x) >> 6;
  int lane = threadIdx.x & 63;
  if (wid >= n) return;
  int beg = R.rowptr[wid], end = R.rowptr[wid + 1];
  float x1i = R.x1[wid];
  float acc0 = 0.f, acc1 = 0.f, acc2 = 0.f, acc3 = 0.f;
  float wsumL = 0.f;
  for (int c = beg; c < end; c += 64) {
    int idx = c + lane;
    int t = 0;
    float wv = 0.f;
    if (idx < end) {
      t = R.tsorted[idx];
      wv = __expf(leaky02(x1i + R.h1[t]));
    }
    wsumL += wv;
    int ne = min(64, end - c);
    int j = 0;
    for (; j + 4 <= ne; j += 4) {
      int t0 = __shfl(t, j),     t1 = __shfl(t, j + 1);
      int t2 = __shfl(t, j + 2), t3 = __shfl(t, j + 3);
      float w0 = __shfl(wv, j),     w1 = __shfl(wv, j + 1);
      float w2_ = __shfl(wv, j + 2), w3 = __shfl(wv, j + 3);
      float v0 = __half2float(R.h16[(size_t)t0 * DD + lane]);
      float v1 = __half2float(R.h16[(size_t)t1 * DD + lane]);
      float v2 = __half2float(R.h16[(size_t)t2 * DD + lane]);
      float v3 = __half2float(R.h16[(size_t)t3 * DD + lane]);
      acc0 = fmaf(w0, v0, acc0);
      acc1 = fmaf(w1, v1, acc1);
      acc2 = fmaf(w2_, v2, acc2);
      acc3 = fmaf(w3, v3, acc3);
    }
    for (; j < ne; ++j) {
      int t0 = __shfl(t, j);
      float w0 = __shfl(wv, j);
      acc0 = fmaf(w0, __half2float(R.h16[(size_t)t0 * DD + lane]), acc0);
    }
  }
  float wsum = wred(wsumL);
  float w2v = R.w2[wid];
  float num = fmaf(w2v, R.x[(size_t)wid * DD + lane], (acc0 + acc1) + (acc2 + acc3));
  R.out[(size_t)wid * DD + lane] = num / (wsum + w2v);
}

// ---------------- semantic attention partial sums ----------------
__global__ __launch_bounds__(256) void sem_kernel(
    const float* __restrict__ eA0, const float* __restrict__ eA1,
    const float* __restrict__ eP0, const float* __restrict__ eP1,
    const float* __restrict__ Wa, const float* __restrict__ ba, const float* __restrict__ qa,
    const float* __restrict__ Wp, const float* __restrict__ bp, const float* __restrict__ qp,
    float* __restrict__ psums)
{
  int side = blockIdx.y;
  const float* e0 = side ? eP0 : eA0;
  const float* e1 = side ? eP1 : eA1;
  const float* W = side ? Wp : Wa;
  const float* b = side ? bp : ba;
  const float* q = side ? qp : qa;

  __shared__ float Ws[DD * NSEM];
  __shared__ float zs[8][2][DD];
  __shared__ float red0[256], red1[256];
  int tid = threadIdx.x;
  {
    const float4* W4 = (const float4*)W;
    float4* Ws4 = (float4*)Ws;
    #pragma unroll
    for (int j = 0; j < 8; ++j) Ws4[tid + j * 256] = W4[tid + j * 256];
  }
  int slot = tid >> 7;
  int k = tid & 127;
  float bk = b[k], qk = q[k];
  int base = blockIdx.x * 64;
  float sum0 = 0.f, sum1 = 0.f;
  for (int it = 0; it < 8; ++it) {
    #pragma unroll
    for (int j = 0; j < 4; ++j) {
      int idx = tid + j * 256;
      int nn = idx >> 7, m = (idx >> 6) & 1, d = idx & 63;
      int node = base + it * 8 + nn;
      zs[nn][m][d] = (m ? e1 : e0)[(size_t)node * DD + d];
    }
    __syncthreads();
    float acc[4][2];
    #pragma unroll
    for (int nn = 0; nn < 4; ++nn) { acc[nn][0] = bk; acc[nn][1] = bk; }
    #pragma unroll 8
    for (int d = 0; d < DD; ++d) {
      float w = Ws[d * NSEM + k];
      #pragma unroll
      for (int nn = 0; nn < 4; ++nn) {
        acc[nn][0] = fmaf(zs[slot * 4 + nn][0][d], w, acc[nn][0]);
        acc[nn][1] = fmaf(zs[slot * 4 + nn][1][d], w, acc[nn][1]);
      }
    }
    #pragma unroll
    for (int nn = 0; nn < 4; ++nn) {
      sum0 += tanh_fast(acc[nn][0]) * qk;
      sum1 += tanh_fast(acc[nn][1]) * qk;
    }
    __syncthreads();
  }
  red0[tid] = sum0;
  red1[tid] = sum1;
  __syncthreads();
  for (int off = 128; off; off >>= 1) {
    if (tid < off) { red0[tid] += red0[tid + off]; red1[tid] += red1[tid + off]; }
    __syncthreads();
  }
  if (tid == 0) {
    int idx = (side * gridDim.x + blockIdx.x) * 2;
    psums[idx + 0] = red0[0];
    psums[idx + 1] = red1[0];
  }
}

__global__ __launch_bounds__(256) void beta_kernel(const float* __restrict__ psums,
    float* __restrict__ beta, int nblk, float invn)
{
  __shared__ float s[4][256];
  int t = threadIdx.x;
  float a0 = 0.f, a1 = 0.f, p0 = 0.f, p1 = 0.f;
  for (int i = t; i < nblk; i += 256) {
    a0 += psums[i * 2];
    a1 += psums[i * 2 + 1];
    p0 += psums[(nblk + i) * 2];
    p1 += psums[(nblk + i) * 2 + 1];
  }
  s[0][t] = a0; s[1][t] = a1; s[2][t] = p0; s[3][t] = p1;
  __syncthreads();
  for (int off = 128; off; off >>= 1) {
    if (t < off) {
      s[0][t] += s[0][t + off]; s[1][t] += s[1][t + off];
      s[2][t] += s[2][t + off]; s[3][t] += s[3][t + off];
    }
    __syncthreads();
  }
  if (t == 0) {
    float m0 = s[0][0] * invn, m1 = s[1][0] * invn;
    float mx = fmaxf(m0, m1);
    float x0 = __expf(m0 - mx), x1 = __expf(m1 - mx);
    float inv = 1.f / (x0 + x1);
    beta[0] = x0 * inv; beta[1] = x1 * inv;
    m0 = s[2][0] * invn; m1 = s[3][0] * invn;
    mx = fmaxf(m0, m1);
    x0 = __expf(m0 - mx); x1 = __expf(m1 - mx);
    inv = 1.f / (x0 + x1);
    beta[2] = x0 * inv; beta[3] = x1 * inv;
  }
}

// ---------------- combine + ELU + fp16 copy + fused next-hop h1 ----------------
__global__ __launch_bounds__(256) void combine_h1_kernel(
    const float* __restrict__ eA0, const float* __restrict__ eA1,
    const float* __restrict__ eP0, const float* __restrict__ eP1,
    const float* __restrict__ beta, float* __restrict__ hA, float* __restrict__ hP,
    __half* __restrict__ hA16, __half* __restrict__ hP16,
    const float* __restrict__ a2_aa_n, const float* __restrict__ a2_pa_n,
    const float* __restrict__ a2_ap_n, const float* __restrict__ a2_pp_n,
    float* __restrict__ h1_ap, float* __restrict__ h1_aa,
    float* __restrict__ h1_pa, float* __restrict__ h1_pp, int has_next)
{
  int side = blockIdx.y;
  int wid = threadIdx.x >> 6, lane = threadIdx.x & 63;
  int row = blockIdx.x * 4 + wid;
  const float* e0 = side ? eP0 : eA0;
  const float* e1 = side ? eP1 : eA1;
  float b0 = beta[side * 2], b1 = beta[side * 2 + 1];
  float v0 = e0[(size_t)row * DD + lane];
  float v1 = e1[(size_t)row * DD + lane];
  float t = b0 * v0 + b1 * v1;
  float v = t > 0.f ? t : (__expf(t) - 1.f);
  (side ? hP : hA)[(size_t)row * DD + lane] = v;
  (side ? hP16 : hA16)[(size_t)row * DD + lane] = __float2half(v);
  if (has_next) {
    const float* ax = side ? a2_ap_n : a2_aa_n;
    const float* ay = side ? a2_pp_n : a2_pa_n;
    float rx = wred(v * ax[lane]);
    float ry = wred(v * ay[lane]);
    if (lane == 0) {
      if (side) { h1_ap[row] = rx; h1_pp[row] = ry; }
      else      { h1_aa[row] = rx; h1_pa[row] = ry; }
    }
  }
}

// ---------------- final projection ----------------
__global__ void final_kernel(const float* __restrict__ hA, const float* __restrict__ W2,
    const float* __restrict__ b2, float* __restrict__ out, int n)
{
  int j = blockIdx.x * blockDim.x + threadIdx.x;
  if (j >= n) return;
  float acc0 = b2[0], acc1 = b2[1], acc2 = b2[2], acc3 = b2[3];
  const float4* hrow = (const float4*)(hA + (size_t)j * DD);
  #pragma unroll
  for (int d4 = 0; d4 < 16; ++d4) {
    float4 v = hrow[d4];
    #pragma unroll
    for (int c = 0; c < 4; ++c) {
      int d = d4 * 4 + c;
      float vv = (&v.x)[c];
      acc0 = fmaf(vv, W2[d * 4 + 0], acc0);
      acc1 = fmaf(vv, W2[d * 4 + 1], acc1);
      acc2 = fmaf(vv, W2[d * 4 + 2], acc2);
      acc3 = fmaf(vv, W2[d * 4 + 3], acc3);
    }
  }
  ((float4*)out)[j] = make_float4(acc0, acc1, acc2, acc3);
}

extern "C" void kernel_launch(void* const* d_in, const int* in_sizes, int n_in,
                              void* d_out, int out_size, void* d_ws, size_t ws_size,
                              hipStream_t stream)
{
  const float* x_author = (const float*)d_in[0];
  const float* x_paper  = (const float*)d_in[1];
  const float* W1_a = (const float*)d_in[2];
  const float* b1_a = (const float*)d_in[3];
  const float* W1_p = (const float*)d_in[4];
  const float* b1_p = (const float*)d_in[5];
  const float* a1_ap = (const float*)d_in[6];
  const float* a2_ap = (const float*)d_in[7];
  const float* a1_aa = (const float*)d_in[8];
  const float* a2_aa = (const float*)d_in[9];
  const float* a1_pa = (const float*)d_in[10];
  const float* a2_pa = (const float*)d_in[11];
  const float* a1_pp = (const float*)d_in[12];
  const float* a2_pp = (const float*)d_in[13];
  const float* semW_a = (const float*)d_in[14];
  const float* semb_a = (const float*)d_in[15];
  const float* semq_a = (const float*)d_in[16];
  const float* semW_p = (const float*)d_in[17];
  const float* semb_p = (const float*)d_in[18];
  const float* semq_p = (const float*)d_in[19];
  const float* W2 = (const float*)d_in[20];
  const float* b2 = (const float*)d_in[21];
  const int* ei[4] = {(const int*)d_in[22], (const int*)d_in[23],
                      (const int*)d_in[24], (const int*)d_in[25]};

  // ---- workspace carve ----
  char* w = (char*)d_ws;
  auto alloc = [&](size_t bytes) -> void* {
    void* p = (void*)w;
    w += (bytes + 255) & ~(size_t)255;
    return p;
  };
  const size_t matB = (size_t)NN * DD * sizeof(float);
  float* xA  = (float*)alloc(matB);
  float* xP  = (float*)alloc(matB);
  float* hA  = (float*)alloc(matB);
  float* hP  = (float*)alloc(matB);
  float* eA0 = (float*)alloc(matB);
  float* eA1 = (float*)alloc(matB);
  float* eP0 = (float*)alloc(matB);
  float* eP1 = (float*)alloc(matB);
  // fp16 gather buffers; hA16 aliases xA16 (proj rewrites each call before use)
  __half* xA16 = (__half*)alloc(matB / 2);
  __half* xP16 = (__half*)alloc(matB / 2);
  __half* hA16 = xA16;
  __half* hP16 = xP16;
  // pairbuf (4*E int2 = 25.6 MB) aliases eA0.. (CSR build precedes e-buffer writes)
  int2* pairbuf = (int2*)eA0;
  int* rowptr[4]; int* tsorted[4];
  for (int r = 0; r < 4; ++r) {
    rowptr[r]  = (int*)alloc((NN + 1) * sizeof(int));
    tsorted[r] = (int*)alloc((size_t)EE * sizeof(int));
  }
  int* counts = (int*)alloc((size_t)4 * NN * sizeof(int));
  int* bcur   = (int*)alloc((size_t)4 * NBK * sizeof(int));
  float* x1all = (float*)alloc((size_t)4 * NHOP * NN * sizeof(float));
  float* w2all = (float*)alloc((size_t)4 * NHOP * NN * sizeof(float));
  float* h1b[4];
  for (int r = 0; r < 4; ++r) h1b[r] = (float*)alloc(NN * sizeof(float));
  float* psums = (float*)alloc((size_t)2 * NBK * 2 * sizeof(float));
  float* betab = (float*)alloc(64);

  // ---- projections ----
  proj_gemm_relu<<<NN / PBM, 512, 0, stream>>>(x_author, W1_a, b1_a, xA, xA16, NN, 334);
  proj_gemm_relu<<<NN / PBM, 512, 0, stream>>>(x_paper,  W1_p, b1_p, xP, xP16, NN, 512);

  // ---- CSR build ----
  const int EB = (EE + 255) / 256;
  zero_i32<<<(4 * NN + 255) / 256, 256, 0, stream>>>(counts, 4 * NN);
  hist4_kernel<<<dim3(EB, 4), 256, 0, stream>>>(ei[0], ei[1], ei[2], ei[3], counts, EE, NN);
  scan4_kernel<<<4, 1024, 0, stream>>>(counts, rowptr[0], rowptr[1], rowptr[2], rowptr[3],
                                       bcur, NN);
  binA_kernel<<<dim3((EE + BINCH - 1) / BINCH, 4), 256, 0, stream>>>(
      ei[0], ei[1], ei[2], ei[3], bcur, pairbuf, EE);
  binB_kernel<<<dim3(NBK, 4), 256, 0, stream>>>(pairbuf,
      rowptr[0], rowptr[1], rowptr[2], rowptr[3],
      tsorted[0], tsorted[1], tsorted[2], tsorted[3], EE);

  // ---- upfront x1/w2 (all hops) + hop-0 h1 ----
  precompute_xw<<<dim3(NN / 16, 2), 1024, 0, stream>>>(
      xA, xP, a1_ap, a2_ap, a1_aa, a2_aa, a1_pa, a2_pa, a1_pp, a2_pp,
      x1all, w2all, h1b[0], h1b[1], h1b[2], h1b[3]);

  // ---- hop loop ----
  const int AGG_GRID = (NN * 64) / 256;
  for (int i = 0; i < NHOP; ++i) {
    #define X1(r) (x1all + ((size_t)(r) * NHOP + i) * NN)
    #define W2P(r) (w2all + ((size_t)(r) * NHOP + i) * NN)
    // gather sources are constant pointers: hP16==xP16, hA16==xA16 (aliased)
    AggRel r0 = {xA, hP16, X1(0), W2P(0), h1b[0], rowptr[0], tsorted[0], eA0};
    AggRel r1 = {xA, hA16, X1(1), W2P(1), h1b[1], rowptr[1], tsorted[1], eA1};
    AggRel r2 = {xP, hA16, X1(2), W2P(2), h1b[2], rowptr[2], tsorted[2], eP0};
    AggRel r3 = {xP, hP16, X1(3), W2P(3), h1b[3], rowptr[3], tsorted[3], eP1};
    agg4_kernel<<<dim3(AGG_GRID, 4), 256, 0, stream>>>(r0, r1, r2, r3, NN);

    sem_kernel<<<dim3(NN / 64, 2), 256, 0, stream>>>(
        eA0, eA1, eP0, eP1,
        semW_a + (size_t)i * DD * NSEM, semb_a + i * NSEM, semq_a + i * NSEM,
        semW_p + (size_t)i * DD * NSEM, semb_p + i * NSEM, semq_p + i * NSEM,
        psums);
    beta_kernel<<<1, 256, 0, stream>>>(psums, betab, NN / 64, 1.f / NN);

    int inext = (i + 1 < NHOP) ? (i + 1) : i;
    combine_h1_kernel<<<dim3(NN / 4, 2), 256, 0, stream>>>(
        eA0, eA1, eP0, eP1, betab, hA, hP, hA16, hP16,
        a2_aa + inext * DD, a2_pa + inext * DD, a2_ap + inext * DD, a2_pp + inext * DD,
        h1b[0], h1b[1], h1b[2], h1b[3], (i + 1 < NHOP) ? 1 : 0);
  }

  final_kernel<<<(NN + 255) / 256, 256, 0, stream>>>(hA, W2, b2, (float*)d_out, NN);
}

// Round 5
// 1334.661 us; speedup vs baseline: 2.5518x; 1.1420x over previous
//
#include <hip/hip_runtime.h>
#include <hip/hip_fp16.h>

#define NN 40000
#define DD 64
#define EE 800000
#define NHOP 5
#define NSEM 128
#define NBK 625          // NN/64 buckets for binned scatter
#define BINCH 8192       // edges per binA/binCount block

__device__ __forceinline__ float leaky02(float v) { return v > 0.f ? v : 0.2f * v; }
__device__ __forceinline__ float tanh_fast(float x) {
  return 1.f - 2.f / (__expf(2.f * x) + 1.f);
}
__device__ __forceinline__ float wred(float x) {
  #pragma unroll
  for (int m = 1; m < 64; m <<= 1) x += __shfl_xor(x, m);
  return x;
}

// ---------------- zero kernel ----------------
__global__ void zero_i32(int* __restrict__ p, int n) {
  int i = blockIdx.x * blockDim.x + threadIdx.x;
  if (i < n) p[i] = 0;
}

// ---------------- projection GEMM + bias + relu (f32 out + fp16 copy) ----------------
#define PBM 64
#define PBK 64
__global__ __launch_bounds__(512) void proj_gemm_relu(
    const float* __restrict__ X, const float* __restrict__ W,
    const float* __restrict__ bias, float* __restrict__ out,
    __half* __restrict__ out16, int n, int K)
{
  __shared__ float As[PBM][PBK + 1];
  __shared__ float Bs[PBK][DD];
  int tid = threadIdx.x;
  int tx = tid & 15;
  int ty = tid >> 4;
  int row0 = blockIdx.x * PBM;
  float acc[2][4] = {{0.f}};
  int nk = (K + PBK - 1) / PBK;
  for (int kt = 0; kt < nk; ++kt) {
    int k0 = kt * PBK;
    #pragma unroll
    for (int j = 0; j < 8; ++j) {
      int idx = tid + j * 512;
      int r = idx >> 6, c = idx & 63;
      int gk = k0 + c;
      As[r][c] = (gk < K) ? X[(size_t)(row0 + r) * K + gk] : 0.f;
    }
    #pragma unroll
    for (int j = 0; j < 2; ++j) {
      int idx = tid + j * 512;
      int r = idx >> 4, c4 = idx & 15;
      int gk = k0 + r;
      float4 v = (gk < K) ? ((const float4*)(W + (size_t)gk * DD))[c4]
                          : make_float4(0.f, 0.f, 0.f, 0.f);
      ((float4*)&Bs[r][0])[c4] = v;
    }
    __syncthreads();
    #pragma unroll 8
    for (int kk = 0; kk < PBK; ++kk) {
      float a0 = As[ty * 2][kk];
      float a1 = As[ty * 2 + 1][kk];
      float4 bv = ((float4*)&Bs[kk][0])[tx];
      acc[0][0] = fmaf(a0, bv.x, acc[0][0]);
      acc[0][1] = fmaf(a0, bv.y, acc[0][1]);
      acc[0][2] = fmaf(a0, bv.z, acc[0][2]);
      acc[0][3] = fmaf(a0, bv.w, acc[0][3]);
      acc[1][0] = fmaf(a1, bv.x, acc[1][0]);
      acc[1][1] = fmaf(a1, bv.y, acc[1][1]);
      acc[1][2] = fmaf(a1, bv.z, acc[1][2]);
      acc[1][3] = fmaf(a1, bv.w, acc[1][3]);
    }
    __syncthreads();
  }
  float4 bb = ((const float4*)bias)[tx];
  #pragma unroll
  for (int i = 0; i < 2; ++i) {
    int gr = row0 + ty * 2 + i;
    float4 v;
    v.x = fmaxf(acc[i][0] + bb.x, 0.f);
    v.y = fmaxf(acc[i][1] + bb.y, 0.f);
    v.z = fmaxf(acc[i][2] + bb.z, 0.f);
    v.w = fmaxf(acc[i][3] + bb.w, 0.f);
    ((float4*)(out + (size_t)gr * DD))[tx] = v;
    __half2 p0 = __floats2half2_rn(v.x, v.y);
    __half2 p1 = __floats2half2_rn(v.z, v.w);
    ((__half2*)(out16 + (size_t)gr * DD))[tx * 2 + 0] = p0;
    ((__half2*)(out16 + (size_t)gr * DD))[tx * 2 + 1] = p1;
  }
}

// ---------------- CSR build: bucket counts (LDS-privatized) ----------------
__global__ __launch_bounds__(256) void binCount_kernel(
    const int* __restrict__ e0, const int* __restrict__ e1,
    const int* __restrict__ e2, const int* __restrict__ e3,
    int* __restrict__ bcnt, int e)
{
  int rel = blockIdx.y;
  const int* S = rel == 0 ? e0 : rel == 1 ? e1 : rel == 2 ? e2 : e3;
  __shared__ int cnt[NBK];
  int tid = threadIdx.x;
  for (int b = tid; b < NBK; b += 256) cnt[b] = 0;
  __syncthreads();
  int e0i = blockIdx.x * BINCH;
  int ne = min(BINCH, e - e0i);
  for (int i = tid; i < ne; i += 256) atomicAdd(&cnt[S[e0i + i] >> 6], 1);
  __syncthreads();
  for (int b = tid; b < NBK; b += 256)
    if (cnt[b]) atomicAdd(&bcnt[rel * NBK + b], cnt[b]);
}

// bucket scan -> bucket bases + cursor seed; also sets rowptr[NN]=E
__global__ __launch_bounds__(1024) void bucketScan_kernel(
    const int* __restrict__ bcnt, int* __restrict__ bbase, int* __restrict__ bcur,
    int* __restrict__ rp0, int* __restrict__ rp1, int* __restrict__ rp2,
    int* __restrict__ rp3, int e)
{
  int rel = blockIdx.x;
  __shared__ int sh[1024];
  int t = threadIdx.x;
  int v = (t < NBK) ? bcnt[rel * NBK + t] : 0;
  sh[t] = v;
  __syncthreads();
  for (int off = 1; off < 1024; off <<= 1) {
    int y = (t >= off) ? sh[t - off] : 0;
    __syncthreads();
    sh[t] += y;
    __syncthreads();
  }
  if (t < NBK) {
    int base = sh[t] - v;
    bbase[rel * (NBK + 1) + t] = base;
    bcur[rel * NBK + t] = base;
  }
  if (t == 0) {
    bbase[rel * (NBK + 1) + NBK] = e;
    (rel == 0 ? rp0 : rel == 1 ? rp1 : rel == 2 ? rp2 : rp3)[NN] = e;
  }
}

// pass A: bin edges into buckets, packed u32 = (s&63)<<16 | t
__global__ __launch_bounds__(256) void binA_kernel(
    const int* __restrict__ e0, const int* __restrict__ e1,
    const int* __restrict__ e2, const int* __restrict__ e3,
    int* __restrict__ bcur, unsigned* __restrict__ pairbuf, int e)
{
  int rel = blockIdx.y;
  const int* S = rel == 0 ? e0 : rel == 1 ? e1 : rel == 2 ? e2 : e3;
  const int* T = S + e;
  unsigned* pb = pairbuf + (size_t)rel * e;
  __shared__ int cnt[NBK], base[NBK], cnt2[NBK];
  int tid = threadIdx.x;
  for (int b = tid; b < NBK; b += 256) { cnt[b] = 0; cnt2[b] = 0; }
  __syncthreads();
  int e0i = blockIdx.x * BINCH;
  int ne = min(BINCH, e - e0i);
  for (int i = tid; i < ne; i += 256) atomicAdd(&cnt[S[e0i + i] >> 6], 1);
  __syncthreads();
  for (int b = tid; b < NBK; b += 256)
    base[b] = cnt[b] ? atomicAdd(&bcur[rel * NBK + b], cnt[b]) : 0;
  __syncthreads();
  for (int i = tid; i < ne; i += 256) {
    int s = S[e0i + i];
    int t = T[e0i + i];
    int b = s >> 6;
    int off = atomicAdd(&cnt2[b], 1);
    pb[base[b] + off] = ((unsigned)(s & 63) << 16) | (unsigned)t;
  }
}

// pass B: per bucket — local per-node counts, wave prefix -> rowptr, place targets
__global__ __launch_bounds__(256) void binB_kernel(
    const unsigned* __restrict__ pairbuf, const int* __restrict__ bbase,
    int* __restrict__ rp0, int* __restrict__ rp1, int* __restrict__ rp2,
    int* __restrict__ rp3,
    int* __restrict__ ts0, int* __restrict__ ts1, int* __restrict__ ts2,
    int* __restrict__ ts3, int e)
{
  int rel = blockIdx.y;
  int* rowptr = rel == 0 ? rp0 : rel == 1 ? rp1 : rel == 2 ? rp2 : rp3;
  int* ts = rel == 0 ? ts0 : rel == 1 ? ts1 : rel == 2 ? ts2 : ts3;
  const unsigned* pb = pairbuf + (size_t)rel * e;
  int b = blockIdx.x;
  int bstart = bbase[rel * (NBK + 1) + b];
  int bend   = bbase[rel * (NBK + 1) + b + 1];
  __shared__ int ncnt[64], cur[64];
  int tid = threadIdx.x;
  if (tid < 64) ncnt[tid] = 0;
  __syncthreads();
  for (int i = bstart + tid; i < bend; i += 256)
    atomicAdd(&ncnt[(pb[i] >> 16) & 63], 1);
  __syncthreads();
  if (tid < 64) {                       // wave 0: 64-wide inclusive scan
    int v = ncnt[tid];
    int x = v;
    #pragma unroll
    for (int off = 1; off < 64; off <<= 1) {
      int y = __shfl_up(x, off);
      if (tid >= off) x += y;
    }
    int nb = bstart + x - v;            // exclusive prefix
    rowptr[b * 64 + tid] = nb;
    cur[tid] = nb;
  }
  __syncthreads();
  for (int i = bstart + tid; i < bend; i += 256) {
    unsigned u = pb[i];
    int pos = atomicAdd(&cur[(u >> 16) & 63], 1);
    ts[pos] = (int)(u & 0xffffu);
  }
}

// ---------------- upfront: x1/w2 for all hops + hop-0 h1 ----------------
__global__ __launch_bounds__(1024) void precompute_xw(
    const float* __restrict__ xA, const float* __restrict__ xP,
    const float* __restrict__ a1_ap, const float* __restrict__ a2_ap,
    const float* __restrict__ a1_aa, const float* __restrict__ a2_aa,
    const float* __restrict__ a1_pa, const float* __restrict__ a2_pa,
    const float* __restrict__ a1_pp, const float* __restrict__ a2_pp,
    float* __restrict__ x1all, float* __restrict__ w2all,
    float* __restrict__ h1_ap, float* __restrict__ h1_aa,
    float* __restrict__ h1_pa, float* __restrict__ h1_pp)
{
  __shared__ float Ls[8][NHOP * DD];
  int tid = threadIdx.x;
  {
    const float* srcs[8] = {a1_ap, a2_ap, a1_aa, a2_aa, a1_pa, a2_pa, a1_pp, a2_pp};
    for (int i = tid; i < 8 * NHOP * DD; i += 1024)
      Ls[i / (NHOP * DD)][i % (NHOP * DD)] = srcs[i / (NHOP * DD)][i % (NHOP * DD)];
  }
  __syncthreads();
  int side = blockIdx.y;
  int wid = tid >> 6, lane = tid & 63;
  int row = blockIdx.x * 16 + wid;
  float v = (side ? xP : xA)[(size_t)row * DD + lane];
  int r0 = side ? 4 : 0;
  int relA = side ? 2 : 0;
  #pragma unroll
  for (int i = 0; i < NHOP; ++i) {
    float r1 = wred(v * Ls[r0 + 0][i * DD + lane]);
    float r2 = wred(v * Ls[r0 + 1][i * DD + lane]);
    float r3 = wred(v * Ls[r0 + 2][i * DD + lane]);
    float r4 = wred(v * Ls[r0 + 3][i * DD + lane]);
    if (lane == 0) {
      x1all[((size_t)(relA + 0) * NHOP + i) * NN + row] = r1;
      w2all[((size_t)(relA + 0) * NHOP + i) * NN + row] = __expf(leaky02(r1 + r2));
      x1all[((size_t)(relA + 1) * NHOP + i) * NN + row] = r3;
      w2all[((size_t)(relA + 1) * NHOP + i) * NN + row] = __expf(leaky02(r3 + r4));
      if (i == 0) (side ? h1_pp : h1_aa)[row] = r4;
    }
    if (i == 0) {
      float r5 = wred(v * Ls[side ? 1 : 5][lane]);
      if (lane == 0) (side ? h1_ap : h1_pa)[row] = r5;
    }
  }
}

// ---------------- fused edge aggregation: shuffle-score + fp16 gather ----------------
struct AggRel {
  const float* x; const __half* h16; const float* x1; const float* w2; const float* h1;
  const int* rowptr; const int* tsorted; float* out;
};

__global__ __launch_bounds__(256) void agg4_kernel(AggRel r0, AggRel r1, AggRel r2,
                                                   AggRel r3, int n)
{
  AggRel R;
  switch (blockIdx.y) {
    case 0: R = r0; break;
    case 1: R = r1; break;
    case 2: R = r2; break;
    default: R = r3; break;
  }
  int wid = (blockIdx.x * blockDim.x + threadIdx.x) >> 6;
  int lane = threadIdx.x & 63;
  if (wid >= n) return;
  int beg = R.rowptr[wid], end = R.rowptr[wid + 1];
  float x1i = R.x1[wid];
  float acc0 = 0.f, acc1 = 0.f, acc2 = 0.f, acc3 = 0.f;
  float wsumL = 0.f;
  for (int c = beg; c < end; c += 64) {
    int idx = c + lane;
    int t = 0;
    float wv = 0.f;
    if (idx < end) {
      t = R.tsorted[idx];
      wv = __expf(leaky02(x1i + R.h1[t]));
    }
    wsumL += wv;
    int ne = min(64, end - c);
    int j = 0;
    for (; j + 4 <= ne; j += 4) {
      int t0 = __shfl(t, j),     t1 = __shfl(t, j + 1);
      int t2 = __shfl(t, j + 2), t3 = __shfl(t, j + 3);
      float w0 = __shfl(wv, j),     w1 = __shfl(wv, j + 1);
      float w2_ = __shfl(wv, j + 2), w3 = __shfl(wv, j + 3);
      float v0 = __half2float(R.h16[(size_t)t0 * DD + lane]);
      float v1 = __half2float(R.h16[(size_t)t1 * DD + lane]);
      float v2 = __half2float(R.h16[(size_t)t2 * DD + lane]);
      float v3 = __half2float(R.h16[(size_t)t3 * DD + lane]);
      acc0 = fmaf(w0, v0, acc0);
      acc1 = fmaf(w1, v1, acc1);
      acc2 = fmaf(w2_, v2, acc2);
      acc3 = fmaf(w3, v3, acc3);
    }
    for (; j < ne; ++j) {
      int t0 = __shfl(t, j);
      float w0 = __shfl(wv, j);
      acc0 = fmaf(w0, __half2float(R.h16[(size_t)t0 * DD + lane]), acc0);
    }
  }
  float wsum = wred(wsumL);
  float w2v = R.w2[wid];
  float num = fmaf(w2v, R.x[(size_t)wid * DD + lane], (acc0 + acc1) + (acc2 + acc3));
  R.out[(size_t)wid * DD + lane] = num / (wsum + w2v);
}

// ---------------- semantic attention partial sums ----------------
__global__ __launch_bounds__(256) void sem_kernel(
    const float* __restrict__ eA0, const float* __restrict__ eA1,
    const float* __restrict__ eP0, const float* __restrict__ eP1,
    const float* __restrict__ Wa, const float* __restrict__ ba, const float* __restrict__ qa,
    const float* __restrict__ Wp, const float* __restrict__ bp, const float* __restrict__ qp,
    float* __restrict__ psums)
{
  int side = blockIdx.y;
  const float* e0 = side ? eP0 : eA0;
  const float* e1 = side ? eP1 : eA1;
  const float* W = side ? Wp : Wa;
  const float* b = side ? bp : ba;
  const float* q = side ? qp : qa;

  __shared__ float Ws[DD * NSEM];
  __shared__ float zs[8][2][DD];
  __shared__ float red0[256], red1[256];
  int tid = threadIdx.x;
  {
    const float4* W4 = (const float4*)W;
    float4* Ws4 = (float4*)Ws;
    #pragma unroll
    for (int j = 0; j < 8; ++j) Ws4[tid + j * 256] = W4[tid + j * 256];
  }
  int slot = tid >> 7;
  int k = tid & 127;
  float bk = b[k], qk = q[k];
  int base = blockIdx.x * 64;
  float sum0 = 0.f, sum1 = 0.f;
  for (int it = 0; it < 8; ++it) {
    #pragma unroll
    for (int j = 0; j < 4; ++j) {
      int idx = tid + j * 256;
      int nn = idx >> 7, m = (idx >> 6) & 1, d = idx & 63;
      int node = base + it * 8 + nn;
      zs[nn][m][d] = (m ? e1 : e0)[(size_t)node * DD + d];
    }
    __syncthreads();
    float acc[4][2];
    #pragma unroll
    for (int nn = 0; nn < 4; ++nn) { acc[nn][0] = bk; acc[nn][1] = bk; }
    #pragma unroll 8
    for (int d = 0; d < DD; ++d) {
      float w = Ws[d * NSEM + k];
      #pragma unroll
      for (int nn = 0; nn < 4; ++nn) {
        acc[nn][0] = fmaf(zs[slot * 4 + nn][0][d], w, acc[nn][0]);
        acc[nn][1] = fmaf(zs[slot * 4 + nn][1][d], w, acc[nn][1]);
      }
    }
    #pragma unroll
    for (int nn = 0; nn < 4; ++nn) {
      sum0 += tanh_fast(acc[nn][0]) * qk;
      sum1 += tanh_fast(acc[nn][1]) * qk;
    }
    __syncthreads();
  }
  red0[tid] = sum0;
  red1[tid] = sum1;
  __syncthreads();
  for (int off = 128; off; off >>= 1) {
    if (tid < off) { red0[tid] += red0[tid + off]; red1[tid] += red1[tid + off]; }
    __syncthreads();
  }
  if (tid == 0) {
    int idx = (side * gridDim.x + blockIdx.x) * 2;
    psums[idx + 0] = red0[0];
    psums[idx + 1] = red1[0];
  }
}

__global__ __launch_bounds__(256) void beta_kernel(const float* __restrict__ psums,
    float* __restrict__ beta, int nblk, float invn)
{
  __shared__ float s[4][256];
  int t = threadIdx.x;
  float a0 = 0.f, a1 = 0.f, p0 = 0.f, p1 = 0.f;
  for (int i = t; i < nblk; i += 256) {
    a0 += psums[i * 2];
    a1 += psums[i * 2 + 1];
    p0 += psums[(nblk + i) * 2];
    p1 += psums[(nblk + i) * 2 + 1];
  }
  s[0][t] = a0; s[1][t] = a1; s[2][t] = p0; s[3][t] = p1;
  __syncthreads();
  for (int off = 128; off; off >>= 1) {
    if (t < off) {
      s[0][t] += s[0][t + off]; s[1][t] += s[1][t + off];
      s[2][t] += s[2][t + off]; s[3][t] += s[3][t + off];
    }
    __syncthreads();
  }
  if (t == 0) {
    float m0 = s[0][0] * invn, m1 = s[1][0] * invn;
    float mx = fmaxf(m0, m1);
    float x0 = __expf(m0 - mx), x1 = __expf(m1 - mx);
    float inv = 1.f / (x0 + x1);
    beta[0] = x0 * inv; beta[1] = x1 * inv;
    m0 = s[2][0] * invn; m1 = s[3][0] * invn;
    mx = fmaxf(m0, m1);
    x0 = __expf(m0 - mx); x1 = __expf(m1 - mx);
    inv = 1.f / (x0 + x1);
    beta[2] = x0 * inv; beta[3] = x1 * inv;
  }
}

// ---------------- combine + ELU + fp16 copy + fused next-hop h1 ----------------
__global__ __launch_bounds__(256) void combine_h1_kernel(
    const float* __restrict__ eA0, const float* __restrict__ eA1,
    const float* __restrict__ eP0, const float* __restrict__ eP1,
    const float* __restrict__ beta, float* __restrict__ hA, float* __restrict__ hP,
    __half* __restrict__ hA16, __half* __restrict__ hP16,
    const float* __restrict__ a2_aa_n, const float* __restrict__ a2_pa_n,
    const float* __restrict__ a2_ap_n, const float* __restrict__ a2_pp_n,
    float* __restrict__ h1_ap, float* __restrict__ h1_aa,
    float* __restrict__ h1_pa, float* __restrict__ h1_pp, int has_next)
{
  int side = blockIdx.y;
  int wid = threadIdx.x >> 6, lane = threadIdx.x & 63;
  int row = blockIdx.x * 4 + wid;
  const float* e0 = side ? eP0 : eA0;
  const float* e1 = side ? eP1 : eA1;
  float b0 = beta[side * 2], b1 = beta[side * 2 + 1];
  float v0 = e0[(size_t)row * DD + lane];
  float v1 = e1[(size_t)row * DD + lane];
  float t = b0 * v0 + b1 * v1;
  float v = t > 0.f ? t : (__expf(t) - 1.f);
  (side ? hP : hA)[(size_t)row * DD + lane] = v;
  (side ? hP16 : hA16)[(size_t)row * DD + lane] = __float2half(v);
  if (has_next) {
    const float* ax = side ? a2_ap_n : a2_aa_n;
    const float* ay = side ? a2_pp_n : a2_pa_n;
    float rx = wred(v * ax[lane]);
    float ry = wred(v * ay[lane]);
    if (lane == 0) {
      if (side) { h1_ap[row] = rx; h1_pp[row] = ry; }
      else      { h1_aa[row] = rx; h1_pa[row] = ry; }
    }
  }
}

// ---------------- final projection ----------------
__global__ void final_kernel(const float* __restrict__ hA, const float* __restrict__ W2,
    const float* __restrict__ b2, float* __restrict__ out, int n)
{
  int j = blockIdx.x * blockDim.x + threadIdx.x;
  if (j >= n) return;
  float acc0 = b2[0], acc1 = b2[1], acc2 = b2[2], acc3 = b2[3];
  const float4* hrow = (const float4*)(hA + (size_t)j * DD);
  #pragma unroll
  for (int d4 = 0; d4 < 16; ++d4) {
    float4 v = hrow[d4];
    #pragma unroll
    for (int c = 0; c < 4; ++c) {
      int d = d4 * 4 + c;
      float vv = (&v.x)[c];
      acc0 = fmaf(vv, W2[d * 4 + 0], acc0);
      acc1 = fmaf(vv, W2[d * 4 + 1], acc1);
      acc2 = fmaf(vv, W2[d * 4 + 2], acc2);
      acc3 = fmaf(vv, W2[d * 4 + 3], acc3);
    }
  }
  ((float4*)out)[j] = make_float4(acc0, acc1, acc2, acc3);
}

extern "C" void kernel_launch(void* const* d_in, const int* in_sizes, int n_in,
                              void* d_out, int out_size, void* d_ws, size_t ws_size,
                              hipStream_t stream)
{
  const float* x_author = (const float*)d_in[0];
  const float* x_paper  = (const float*)d_in[1];
  const float* W1_a = (const float*)d_in[2];
  const float* b1_a = (const float*)d_in[3];
  const float* W1_p = (const float*)d_in[4];
  const float* b1_p = (const float*)d_in[5];
  const float* a1_ap = (const float*)d_in[6];
  const float* a2_ap = (const float*)d_in[7];
  const float* a1_aa = (const float*)d_in[8];
  const float* a2_aa = (const float*)d_in[9];
  const float* a1_pa = (const float*)d_in[10];
  const float* a2_pa = (const float*)d_in[11];
  const float* a1_pp = (const float*)d_in[12];
  const float* a2_pp = (const float*)d_in[13];
  const float* semW_a = (const float*)d_in[14];
  const float* semb_a = (const float*)d_in[15];
  const float* semq_a = (const float*)d_in[16];
  const float* semW_p = (const float*)d_in[17];
  const float* semb_p = (const float*)d_in[18];
  const float* semq_p = (const float*)d_in[19];
  const float* W2 = (const float*)d_in[20];
  const float* b2 = (const float*)d_in[21];
  const int* ei[4] = {(const int*)d_in[22], (const int*)d_in[23],
                      (const int*)d_in[24], (const int*)d_in[25]};

  // ---- workspace carve ----
  char* w = (char*)d_ws;
  auto alloc = [&](size_t bytes) -> void* {
    void* p = (void*)w;
    w += (bytes + 255) & ~(size_t)255;
    return p;
  };
  const size_t matB = (size_t)NN * DD * sizeof(float);
  float* xA  = (float*)alloc(matB);
  float* xP  = (float*)alloc(matB);
  float* hA  = (float*)alloc(matB);
  float* hP  = (float*)alloc(matB);
  float* eA0 = (float*)alloc(matB);
  float* eA1 = (float*)alloc(matB);
  float* eP0 = (float*)alloc(matB);
  float* eP1 = (float*)alloc(matB);
  // fp16 gather buffers; hA16 aliases xA16 (proj rewrites each call before use)
  __half* xA16 = (__half*)alloc(matB / 2);
  __half* xP16 = (__half*)alloc(matB / 2);
  __half* hA16 = xA16;
  __half* hP16 = xP16;
  // pairbuf (4*E u32 = 12.8 MB) aliases eA0/eA1 (CSR build precedes e-buffer writes)
  unsigned* pairbuf = (unsigned*)eA0;
  int* rowptr[4]; int* tsorted[4];
  for (int r = 0; r < 4; ++r) {
    rowptr[r]  = (int*)alloc((NN + 1) * sizeof(int));
    tsorted[r] = (int*)alloc((size_t)EE * sizeof(int));
  }
  int* bcnt  = (int*)alloc((size_t)4 * NBK * sizeof(int));
  int* bbase = (int*)alloc((size_t)4 * (NBK + 1) * sizeof(int));
  int* bcur  = (int*)alloc((size_t)4 * NBK * sizeof(int));
  float* x1all = (float*)alloc((size_t)4 * NHOP * NN * sizeof(float));
  float* w2all = (float*)alloc((size_t)4 * NHOP * NN * sizeof(float));
  float* h1b[4];
  for (int r = 0; r < 4; ++r) h1b[r] = (float*)alloc(NN * sizeof(float));
  float* psums = (float*)alloc((size_t)2 * NBK * 2 * sizeof(float));
  float* betab = (float*)alloc(64);

  // ---- projections ----
  proj_gemm_relu<<<NN / PBM, 512, 0, stream>>>(x_author, W1_a, b1_a, xA, xA16, NN, 334);
  proj_gemm_relu<<<NN / PBM, 512, 0, stream>>>(x_paper,  W1_p, b1_p, xP, xP16, NN, 512);

  // ---- CSR build (bucket-level counting; no per-node global histogram) ----
  const int NEB = (EE + BINCH - 1) / BINCH;
  zero_i32<<<(4 * NBK + 255) / 256, 256, 0, stream>>>(bcnt, 4 * NBK);
  binCount_kernel<<<dim3(NEB, 4), 256, 0, stream>>>(ei[0], ei[1], ei[2], ei[3], bcnt, EE);
  bucketScan_kernel<<<4, 1024, 0, stream>>>(bcnt, bbase, bcur,
      rowptr[0], rowptr[1], rowptr[2], rowptr[3], EE);
  binA_kernel<<<dim3(NEB, 4), 256, 0, stream>>>(
      ei[0], ei[1], ei[2], ei[3], bcur, pairbuf, EE);
  binB_kernel<<<dim3(NBK, 4), 256, 0, stream>>>(pairbuf, bbase,
      rowptr[0], rowptr[1], rowptr[2], rowptr[3],
      tsorted[0], tsorted[1], tsorted[2], tsorted[3], EE);

  // ---- upfront x1/w2 (all hops) + hop-0 h1 ----
  precompute_xw<<<dim3(NN / 16, 2), 1024, 0, stream>>>(
      xA, xP, a1_ap, a2_ap, a1_aa, a2_aa, a1_pa, a2_pa, a1_pp, a2_pp,
      x1all, w2all, h1b[0], h1b[1], h1b[2], h1b[3]);

  // ---- hop loop ----
  const int AGG_GRID = (NN * 64) / 256;
  for (int i = 0; i < NHOP; ++i) {
    #define X1(r) (x1all + ((size_t)(r) * NHOP + i) * NN)
    #define W2P(r) (w2all + ((size_t)(r) * NHOP + i) * NN)
    AggRel r0 = {xA, hP16, X1(0), W2P(0), h1b[0], rowptr[0], tsorted[0], eA0};
    AggRel r1 = {xA, hA16, X1(1), W2P(1), h1b[1], rowptr[1], tsorted[1], eA1};
    AggRel r2 = {xP, hA16, X1(2), W2P(2), h1b[2], rowptr[2], tsorted[2], eP0};
    AggRel r3 = {xP, hP16, X1(3), W2P(3), h1b[3], rowptr[3], tsorted[3], eP1};
    agg4_kernel<<<dim3(AGG_GRID, 4), 256, 0, stream>>>(r0, r1, r2, r3, NN);

    sem_kernel<<<dim3(NN / 64, 2), 256, 0, stream>>>(
        eA0, eA1, eP0, eP1,
        semW_a + (size_t)i * DD * NSEM, semb_a + i * NSEM, semq_a + i * NSEM,
        semW_p + (size_t)i * DD * NSEM, semb_p + i * NSEM, semq_p + i * NSEM,
        psums);
    beta_kernel<<<1, 256, 0, stream>>>(psums, betab, NN / 64, 1.f / NN);

    int inext = (i + 1 < NHOP) ? (i + 1) : i;
    combine_h1_kernel<<<dim3(NN / 4, 2), 256, 0, stream>>>(
        eA0, eA1, eP0, eP1, betab, hA, hP, hA16, hP16,
        a2_aa + inext * DD, a2_pa + inext * DD, a2_ap + inext * DD, a2_pp + inext * DD,
        h1b[0], h1b[1], h1b[2], h1b[3], (i + 1 < NHOP) ? 1 : 0);
  }

  final_kernel<<<(NN + 255) / 256, 256, 0, stream>>>(hA, W2, b2, (float*)d_out, NN);
}

// Round 6
// 1237.750 us; speedup vs baseline: 2.7516x; 1.0783x over previous
//
#include <hip/hip_runtime.h>
#include <hip/hip_fp16.h>

#define NN 40000
#define DD 64
#define EE 800000
#define NHOP 5
#define NSEM 128
#define NBK 625          // NN/64 buckets for binned scatter
#define BINCH 8192       // edges per binA/binCount block

__device__ __forceinline__ float leaky02(float v) { return v > 0.f ? v : 0.2f * v; }
__device__ __forceinline__ float tanh_fast(float x) {
  return 1.f - 2.f / (__expf(2.f * x) + 1.f);
}
__device__ __forceinline__ float wred(float x) {
  #pragma unroll
  for (int m = 1; m < 64; m <<= 1) x += __shfl_xor(x, m);
  return x;
}

// ---------------- zero kernel ----------------
__global__ void zero_i32(int* __restrict__ p, int n) {
  int i = blockIdx.x * blockDim.x + threadIdx.x;
  if (i < n) p[i] = 0;
}

// ---------------- projection GEMM + bias + relu (f32 out + fp16 copy) ----------------
#define PBM 64
#define PBK 64
__global__ __launch_bounds__(512) void proj_gemm_relu(
    const float* __restrict__ X, const float* __restrict__ W,
    const float* __restrict__ bias, float* __restrict__ out,
    __half* __restrict__ out16, int n, int K)
{
  __shared__ float As[PBM][PBK + 1];
  __shared__ float Bs[PBK][DD];
  int tid = threadIdx.x;
  int tx = tid & 15;
  int ty = tid >> 4;
  int row0 = blockIdx.x * PBM;
  float acc[2][4] = {{0.f}};
  int nk = (K + PBK - 1) / PBK;
  for (int kt = 0; kt < nk; ++kt) {
    int k0 = kt * PBK;
    #pragma unroll
    for (int j = 0; j < 8; ++j) {
      int idx = tid + j * 512;
      int r = idx >> 6, c = idx & 63;
      int gk = k0 + c;
      As[r][c] = (gk < K) ? X[(size_t)(row0 + r) * K + gk] : 0.f;
    }
    #pragma unroll
    for (int j = 0; j < 2; ++j) {
      int idx = tid + j * 512;
      int r = idx >> 4, c4 = idx & 15;
      int gk = k0 + r;
      float4 v = (gk < K) ? ((const float4*)(W + (size_t)gk * DD))[c4]
                          : make_float4(0.f, 0.f, 0.f, 0.f);
      ((float4*)&Bs[r][0])[c4] = v;
    }
    __syncthreads();
    #pragma unroll 8
    for (int kk = 0; kk < PBK; ++kk) {
      float a0 = As[ty * 2][kk];
      float a1 = As[ty * 2 + 1][kk];
      float4 bv = ((float4*)&Bs[kk][0])[tx];
      acc[0][0] = fmaf(a0, bv.x, acc[0][0]);
      acc[0][1] = fmaf(a0, bv.y, acc[0][1]);
      acc[0][2] = fmaf(a0, bv.z, acc[0][2]);
      acc[0][3] = fmaf(a0, bv.w, acc[0][3]);
      acc[1][0] = fmaf(a1, bv.x, acc[1][0]);
      acc[1][1] = fmaf(a1, bv.y, acc[1][1]);
      acc[1][2] = fmaf(a1, bv.z, acc[1][2]);
      acc[1][3] = fmaf(a1, bv.w, acc[1][3]);
    }
    __syncthreads();
  }
  float4 bb = ((const float4*)bias)[tx];
  #pragma unroll
  for (int i = 0; i < 2; ++i) {
    int gr = row0 + ty * 2 + i;
    float4 v;
    v.x = fmaxf(acc[i][0] + bb.x, 0.f);
    v.y = fmaxf(acc[i][1] + bb.y, 0.f);
    v.z = fmaxf(acc[i][2] + bb.z, 0.f);
    v.w = fmaxf(acc[i][3] + bb.w, 0.f);
    ((float4*)(out + (size_t)gr * DD))[tx] = v;
    __half2 p0 = __floats2half2_rn(v.x, v.y);
    __half2 p1 = __floats2half2_rn(v.z, v.w);
    ((__half2*)(out16 + (size_t)gr * DD))[tx * 2 + 0] = p0;
    ((__half2*)(out16 + (size_t)gr * DD))[tx * 2 + 1] = p1;
  }
}

// ---------------- CSR build: bucket counts (LDS-privatized) ----------------
__global__ __launch_bounds__(256) void binCount_kernel(
    const int* __restrict__ e0, const int* __restrict__ e1,
    const int* __restrict__ e2, const int* __restrict__ e3,
    int* __restrict__ bcnt, int e)
{
  int rel = blockIdx.y;
  const int* S = rel == 0 ? e0 : rel == 1 ? e1 : rel == 2 ? e2 : e3;
  __shared__ int cnt[NBK];
  int tid = threadIdx.x;
  for (int b = tid; b < NBK; b += 256) cnt[b] = 0;
  __syncthreads();
  int e0i = blockIdx.x * BINCH;
  int ne = min(BINCH, e - e0i);
  for (int i = tid; i < ne; i += 256) atomicAdd(&cnt[S[e0i + i] >> 6], 1);
  __syncthreads();
  for (int b = tid; b < NBK; b += 256)
    if (cnt[b]) atomicAdd(&bcnt[rel * NBK + b], cnt[b]);
}

// bucket scan -> bucket bases + cursor seed; also sets rowptr[NN]=E
__global__ __launch_bounds__(1024) void bucketScan_kernel(
    const int* __restrict__ bcnt, int* __restrict__ bbase, int* __restrict__ bcur,
    int* __restrict__ rp0, int* __restrict__ rp1, int* __restrict__ rp2,
    int* __restrict__ rp3, int e)
{
  int rel = blockIdx.x;
  __shared__ int sh[1024];
  int t = threadIdx.x;
  int v = (t < NBK) ? bcnt[rel * NBK + t] : 0;
  sh[t] = v;
  __syncthreads();
  for (int off = 1; off < 1024; off <<= 1) {
    int y = (t >= off) ? sh[t - off] : 0;
    __syncthreads();
    sh[t] += y;
    __syncthreads();
  }
  if (t < NBK) {
    int base = sh[t] - v;
    bbase[rel * (NBK + 1) + t] = base;
    bcur[rel * NBK + t] = base;
  }
  if (t == 0) {
    bbase[rel * (NBK + 1) + NBK] = e;
    (rel == 0 ? rp0 : rel == 1 ? rp1 : rel == 2 ? rp2 : rp3)[NN] = e;
  }
}

// pass A: bin edges into buckets, packed u32 = (s&63)<<16 | t
__global__ __launch_bounds__(256) void binA_kernel(
    const int* __restrict__ e0, const int* __restrict__ e1,
    const int* __restrict__ e2, const int* __restrict__ e3,
    int* __restrict__ bcur, unsigned* __restrict__ pairbuf, int e)
{
  int rel = blockIdx.y;
  const int* S = rel == 0 ? e0 : rel == 1 ? e1 : rel == 2 ? e2 : e3;
  const int* T = S + e;
  unsigned* pb = pairbuf + (size_t)rel * e;
  __shared__ int cnt[NBK], base[NBK], cnt2[NBK];
  int tid = threadIdx.x;
  for (int b = tid; b < NBK; b += 256) { cnt[b] = 0; cnt2[b] = 0; }
  __syncthreads();
  int e0i = blockIdx.x * BINCH;
  int ne = min(BINCH, e - e0i);
  for (int i = tid; i < ne; i += 256) atomicAdd(&cnt[S[e0i + i] >> 6], 1);
  __syncthreads();
  for (int b = tid; b < NBK; b += 256)
    base[b] = cnt[b] ? atomicAdd(&bcur[rel * NBK + b], cnt[b]) : 0;
  __syncthreads();
  for (int i = tid; i < ne; i += 256) {
    int s = S[e0i + i];
    int t = T[e0i + i];
    int b = s >> 6;
    int off = atomicAdd(&cnt2[b], 1);
    pb[base[b] + off] = ((unsigned)(s & 63) << 16) | (unsigned)t;
  }
}

// pass B: per bucket — local per-node counts, wave prefix -> rowptr, place targets
__global__ __launch_bounds__(256) void binB_kernel(
    const unsigned* __restrict__ pairbuf, const int* __restrict__ bbase,
    int* __restrict__ rp0, int* __restrict__ rp1, int* __restrict__ rp2,
    int* __restrict__ rp3,
    int* __restrict__ ts0, int* __restrict__ ts1, int* __restrict__ ts2,
    int* __restrict__ ts3, int e)
{
  int rel = blockIdx.y;
  int* rowptr = rel == 0 ? rp0 : rel == 1 ? rp1 : rel == 2 ? rp2 : rp3;
  int* ts = rel == 0 ? ts0 : rel == 1 ? ts1 : rel == 2 ? ts2 : ts3;
  const unsigned* pb = pairbuf + (size_t)rel * e;
  int b = blockIdx.x;
  int bstart = bbase[rel * (NBK + 1) + b];
  int bend   = bbase[rel * (NBK + 1) + b + 1];
  __shared__ int ncnt[64], cur[64];
  int tid = threadIdx.x;
  if (tid < 64) ncnt[tid] = 0;
  __syncthreads();
  for (int i = bstart + tid; i < bend; i += 256)
    atomicAdd(&ncnt[(pb[i] >> 16) & 63], 1);
  __syncthreads();
  if (tid < 64) {                       // wave 0: 64-wide inclusive scan
    int v = ncnt[tid];
    int x = v;
    #pragma unroll
    for (int off = 1; off < 64; off <<= 1) {
      int y = __shfl_up(x, off);
      if (tid >= off) x += y;
    }
    int nb = bstart + x - v;            // exclusive prefix
    rowptr[b * 64 + tid] = nb;
    cur[tid] = nb;
  }
  __syncthreads();
  for (int i = bstart + tid; i < bend; i += 256) {
    unsigned u = pb[i];
    int pos = atomicAdd(&cur[(u >> 16) & 63], 1);
    ts[pos] = (int)(u & 0xffffu);
  }
}

// ---------------- upfront x1/w2 (all hops) + hop-0 h1 : thread-per-node ----------------
// side A accumulators: k = r*5 + i, r in {a1_ap,a2_ap,a1_aa,a2_aa}; k=20: a2_pa[0]
// side P accumulators: r in {a1_pa,a2_pa,a1_pp,a2_pp}; k=20: a2_ap[0]
__global__ __launch_bounds__(256) void precompute_xw(
    const float* __restrict__ xA, const float* __restrict__ xP,
    const float* __restrict__ a1_ap, const float* __restrict__ a2_ap,
    const float* __restrict__ a1_aa, const float* __restrict__ a2_aa,
    const float* __restrict__ a1_pa, const float* __restrict__ a2_pa,
    const float* __restrict__ a1_pp, const float* __restrict__ a2_pp,
    float* __restrict__ x1all, float* __restrict__ w2all,
    float* __restrict__ h1_ap, float* __restrict__ h1_aa,
    float* __restrict__ h1_pa, float* __restrict__ h1_pp)
{
  int side = blockIdx.y;
  __shared__ float L[21 * DD];
  int tid = threadIdx.x;
  {
    const float* s0 = side ? a1_pa : a1_ap;
    const float* s1 = side ? a2_pa : a2_ap;
    const float* s2 = side ? a1_pp : a1_aa;
    const float* s3 = side ? a2_pp : a2_aa;
    const float* ex = side ? a2_ap : a2_pa;   // hop-0 cross-side extra
    for (int i = tid; i < 21 * DD; i += 256) {
      int k = i >> 6, d = i & 63;
      const float* src = (k < 5) ? s0 : (k < 10) ? s1 : (k < 15) ? s2 : (k < 20) ? s3 : ex;
      int hop = (k < 20) ? (k % 5) : 0;
      L[i] = src[hop * DD + d];
    }
  }
  __syncthreads();
  int j = blockIdx.x * 256 + tid;
  if (j >= NN) return;
  const float4* x4 = (const float4*)((side ? xP : xA) + (size_t)j * DD);
  float acc[21];
  #pragma unroll
  for (int k = 0; k < 21; ++k) acc[k] = 0.f;
  #pragma unroll
  for (int d0 = 0; d0 < 16; ++d0) {
    float4 v = x4[d0];
    #pragma unroll
    for (int c = 0; c < 4; ++c) {
      int d = d0 * 4 + c;
      float xv = (&v.x)[c];
      #pragma unroll
      for (int k = 0; k < 21; ++k) acc[k] = fmaf(xv, L[k * DD + d], acc[k]);
    }
  }
  int relA = side ? 2 : 0;
  #pragma unroll
  for (int i = 0; i < NHOP; ++i) {
    x1all[((size_t)(relA + 0) * NHOP + i) * NN + j] = acc[0 * 5 + i];
    w2all[((size_t)(relA + 0) * NHOP + i) * NN + j] =
        __expf(leaky02(acc[0 * 5 + i] + acc[1 * 5 + i]));
    x1all[((size_t)(relA + 1) * NHOP + i) * NN + j] = acc[2 * 5 + i];
    w2all[((size_t)(relA + 1) * NHOP + i) * NN + j] =
        __expf(leaky02(acc[2 * 5 + i] + acc[3 * 5 + i]));
  }
  if (side) { h1_pp[j] = acc[15]; h1_ap[j] = acc[20]; }
  else      { h1_aa[j] = acc[15]; h1_pa[j] = acc[20]; }
}

// ---------------- fused edge aggregation: shuffle-score + fp16 gather ----------------
struct AggRel {
  const float* x; const __half* h16; const float* x1; const float* w2; const float* h1;
  const int* rowptr; const int* tsorted; float* out;
};

__global__ __launch_bounds__(256) void agg4_kernel(AggRel r0, AggRel r1, AggRel r2,
                                                   AggRel r3, int n)
{
  AggRel R;
  switch (blockIdx.y) {
    case 0: R = r0; break;
    case 1: R = r1; break;
    case 2: R = r2; break;
    default: R = r3; break;
  }
  int wid = (blockIdx.x * blockDim.x + threadIdx.x) >> 6;
  int lane = threadIdx.x & 63;
  if (wid >= n) return;
  int beg = R.rowptr[wid], end = R.rowptr[wid + 1];
  float x1i = R.x1[wid];
  float acc0 = 0.f, acc1 = 0.f, acc2 = 0.f, acc3 = 0.f;
  float wsumL = 0.f;
  for (int c = beg; c < end; c += 64) {
    int idx = c + lane;
    int t = 0;
    float wv = 0.f;
    if (idx < end) {
      t = R.tsorted[idx];
      wv = __expf(leaky02(x1i + R.h1[t]));
    }
    wsumL += wv;
    int ne = min(64, end - c);
    int j = 0;
    for (; j + 4 <= ne; j += 4) {
      int t0 = __shfl(t, j),     t1 = __shfl(t, j + 1);
      int t2 = __shfl(t, j + 2), t3 = __shfl(t, j + 3);
      float w0 = __shfl(wv, j),     w1 = __shfl(wv, j + 1);
      float w2_ = __shfl(wv, j + 2), w3 = __shfl(wv, j + 3);
      float v0 = __half2float(R.h16[(size_t)t0 * DD + lane]);
      float v1 = __half2float(R.h16[(size_t)t1 * DD + lane]);
      float v2 = __half2float(R.h16[(size_t)t2 * DD + lane]);
      float v3 = __half2float(R.h16[(size_t)t3 * DD + lane]);
      acc0 = fmaf(w0, v0, acc0);
      acc1 = fmaf(w1, v1, acc1);
      acc2 = fmaf(w2_, v2, acc2);
      acc3 = fmaf(w3, v3, acc3);
    }
    for (; j < ne; ++j) {
      int t0 = __shfl(t, j);
      float w0 = __shfl(wv, j);
      acc0 = fmaf(w0, __half2float(R.h16[(size_t)t0 * DD + lane]), acc0);
    }
  }
  float wsum = wred(wsumL);
  float w2v = R.w2[wid];
  float num = fmaf(w2v, R.x[(size_t)wid * DD + lane], (acc0 + acc1) + (acc2 + acc3));
  R.out[(size_t)wid * DD + lane] = num / (wsum + w2v);
}

// ---------------- semantic attention partial sums ----------------
__global__ __launch_bounds__(256) void sem_kernel(
    const float* __restrict__ eA0, const float* __restrict__ eA1,
    const float* __restrict__ eP0, const float* __restrict__ eP1,
    const float* __restrict__ Wa, const float* __restrict__ ba, const float* __restrict__ qa,
    const float* __restrict__ Wp, const float* __restrict__ bp, const float* __restrict__ qp,
    float* __restrict__ psums)
{
  int side = blockIdx.y;
  const float* e0 = side ? eP0 : eA0;
  const float* e1 = side ? eP1 : eA1;
  const float* W = side ? Wp : Wa;
  const float* b = side ? bp : ba;
  const float* q = side ? qp : qa;

  __shared__ float Ws[DD * NSEM];
  __shared__ float zs[8][2][DD];
  __shared__ float red0[256], red1[256];
  int tid = threadIdx.x;
  {
    const float4* W4 = (const float4*)W;
    float4* Ws4 = (float4*)Ws;
    #pragma unroll
    for (int j = 0; j < 8; ++j) Ws4[tid + j * 256] = W4[tid + j * 256];
  }
  int slot = tid >> 7;
  int k = tid & 127;
  float bk = b[k], qk = q[k];
  int base = blockIdx.x * 64;
  float sum0 = 0.f, sum1 = 0.f;
  for (int it = 0; it < 8; ++it) {
    #pragma unroll
    for (int j = 0; j < 4; ++j) {
      int idx = tid + j * 256;
      int nn = idx >> 7, m = (idx >> 6) & 1, d = idx & 63;
      int node = base + it * 8 + nn;
      zs[nn][m][d] = (m ? e1 : e0)[(size_t)node * DD + d];
    }
    __syncthreads();
    float acc[4][2];
    #pragma unroll
    for (int nn = 0; nn < 4; ++nn) { acc[nn][0] = bk; acc[nn][1] = bk; }
    #pragma unroll 8
    for (int d = 0; d < DD; ++d) {
      float w = Ws[d * NSEM + k];
      #pragma unroll
      for (int nn = 0; nn < 4; ++nn) {
        acc[nn][0] = fmaf(zs[slot * 4 + nn][0][d], w, acc[nn][0]);
        acc[nn][1] = fmaf(zs[slot * 4 + nn][1][d], w, acc[nn][1]);
      }
    }
    #pragma unroll
    for (int nn = 0; nn < 4; ++nn) {
      sum0 += tanh_fast(acc[nn][0]) * qk;
      sum1 += tanh_fast(acc[nn][1]) * qk;
    }
    __syncthreads();
  }
  red0[tid] = sum0;
  red1[tid] = sum1;
  __syncthreads();
  for (int off = 128; off; off >>= 1) {
    if (tid < off) { red0[tid] += red0[tid + off]; red1[tid] += red1[tid + off]; }
    __syncthreads();
  }
  if (tid == 0) {
    int idx = (side * gridDim.x + blockIdx.x) * 2;
    psums[idx + 0] = red0[0];
    psums[idx + 1] = red1[0];
  }
}

__global__ __launch_bounds__(256) void beta_kernel(const float* __restrict__ psums,
    float* __restrict__ beta, int nblk, float invn)
{
  __shared__ float s[4][256];
  int t = threadIdx.x;
  float a0 = 0.f, a1 = 0.f, p0 = 0.f, p1 = 0.f;
  for (int i = t; i < nblk; i += 256) {
    a0 += psums[i * 2];
    a1 += psums[i * 2 + 1];
    p0 += psums[(nblk + i) * 2];
    p1 += psums[(nblk + i) * 2 + 1];
  }
  s[0][t] = a0; s[1][t] = a1; s[2][t] = p0; s[3][t] = p1;
  __syncthreads();
  for (int off = 128; off; off >>= 1) {
    if (t < off) {
      s[0][t] += s[0][t + off]; s[1][t] += s[1][t + off];
      s[2][t] += s[2][t + off]; s[3][t] += s[3][t + off];
    }
    __syncthreads();
  }
  if (t == 0) {
    float m0 = s[0][0] * invn, m1 = s[1][0] * invn;
    float mx = fmaxf(m0, m1);
    float x0 = __expf(m0 - mx), x1 = __expf(m1 - mx);
    float inv = 1.f / (x0 + x1);
    beta[0] = x0 * inv; beta[1] = x1 * inv;
    m0 = s[2][0] * invn; m1 = s[3][0] * invn;
    mx = fmaxf(m0, m1);
    x0 = __expf(m0 - mx); x1 = __expf(m1 - mx);
    inv = 1.f / (x0 + x1);
    beta[2] = x0 * inv; beta[3] = x1 * inv;
  }
}

// ---------------- combine both sides (pure elementwise, float4) ----------------
__global__ void combine2_kernel(const float4* __restrict__ eA0, const float4* __restrict__ eA1,
    const float4* __restrict__ eP0, const float4* __restrict__ eP1,
    const float* __restrict__ beta, float4* __restrict__ hA, float4* __restrict__ hP,
    __half2* __restrict__ hA16, __half2* __restrict__ hP16, int nvec)
{
  int side = blockIdx.y;
  int i = blockIdx.x * 256 + threadIdx.x;
  if (i >= nvec) return;
  float b0 = beta[side * 2], b1 = beta[side * 2 + 1];
  float4 v0 = (side ? eP0 : eA0)[i];
  float4 v1 = (side ? eP1 : eA1)[i];
  float4 r;
  float t;
  t = b0 * v0.x + b1 * v1.x; r.x = t > 0.f ? t : (__expf(t) - 1.f);
  t = b0 * v0.y + b1 * v1.y; r.y = t > 0.f ? t : (__expf(t) - 1.f);
  t = b0 * v0.z + b1 * v1.z; r.z = t > 0.f ? t : (__expf(t) - 1.f);
  t = b0 * v0.w + b1 * v1.w; r.w = t > 0.f ? t : (__expf(t) - 1.f);
  (side ? hP : hA)[i] = r;
  (side ? hP16 : hA16)[i * 2 + 0] = __floats2half2_rn(r.x, r.y);
  (side ? hP16 : hA16)[i * 2 + 1] = __floats2half2_rn(r.z, r.w);
}

// ---------------- next-hop h1 dots (thread-per-node) ----------------
__global__ __launch_bounds__(256) void h1next_kernel(
    const float* __restrict__ hA, const float* __restrict__ hP,
    const float* __restrict__ a2_ap_n, const float* __restrict__ a2_aa_n,
    const float* __restrict__ a2_pa_n, const float* __restrict__ a2_pp_n,
    float* __restrict__ h1_ap, float* __restrict__ h1_aa,
    float* __restrict__ h1_pa, float* __restrict__ h1_pp)
{
  __shared__ float L[4][DD];
  int tid = threadIdx.x;
  if (tid < 4 * DD) {
    int k = tid >> 6, d = tid & 63;
    const float* src = k == 0 ? a2_ap_n : k == 1 ? a2_aa_n : k == 2 ? a2_pa_n : a2_pp_n;
    L[k][d] = src[d];
  }
  __syncthreads();
  int j = blockIdx.x * 256 + tid;
  if (j >= NN) return;
  const float4* ha4 = (const float4*)(hA + (size_t)j * DD);
  const float4* hp4 = (const float4*)(hP + (size_t)j * DD);
  float s0 = 0.f, s1 = 0.f, s2 = 0.f, s3 = 0.f;
  #pragma unroll
  for (int d0 = 0; d0 < 16; ++d0) {
    float4 a = ha4[d0];
    float4 p = hp4[d0];
    #pragma unroll
    for (int c = 0; c < 4; ++c) {
      int d = d0 * 4 + c;
      float av = (&a.x)[c], pv = (&p.x)[c];
      s0 = fmaf(pv, L[0][d], s0);   // h1_ap = hP . a2_ap
      s1 = fmaf(av, L[1][d], s1);   // h1_aa = hA . a2_aa
      s2 = fmaf(av, L[2][d], s2);   // h1_pa = hA . a2_pa
      s3 = fmaf(pv, L[3][d], s3);   // h1_pp = hP . a2_pp
    }
  }
  h1_ap[j] = s0;
  h1_aa[j] = s1;
  h1_pa[j] = s2;
  h1_pp[j] = s3;
}

// ---------------- final projection ----------------
__global__ void final_kernel(const float* __restrict__ hA, const float* __restrict__ W2,
    const float* __restrict__ b2, float* __restrict__ out, int n)
{
  int j = blockIdx.x * blockDim.x + threadIdx.x;
  if (j >= n) return;
  float acc0 = b2[0], acc1 = b2[1], acc2 = b2[2], acc3 = b2[3];
  const float4* hrow = (const float4*)(hA + (size_t)j * DD);
  #pragma unroll
  for (int d4 = 0; d4 < 16; ++d4) {
    float4 v = hrow[d4];
    #pragma unroll
    for (int c = 0; c < 4; ++c) {
      int d = d4 * 4 + c;
      float vv = (&v.x)[c];
      acc0 = fmaf(vv, W2[d * 4 + 0], acc0);
      acc1 = fmaf(vv, W2[d * 4 + 1], acc1);
      acc2 = fmaf(vv, W2[d * 4 + 2], acc2);
      acc3 = fmaf(vv, W2[d * 4 + 3], acc3);
    }
  }
  ((float4*)out)[j] = make_float4(acc0, acc1, acc2, acc3);
}

extern "C" void kernel_launch(void* const* d_in, const int* in_sizes, int n_in,
                              void* d_out, int out_size, void* d_ws, size_t ws_size,
                              hipStream_t stream)
{
  const float* x_author = (const float*)d_in[0];
  const float* x_paper  = (const float*)d_in[1];
  const float* W1_a = (const float*)d_in[2];
  const float* b1_a = (const float*)d_in[3];
  const float* W1_p = (const float*)d_in[4];
  const float* b1_p = (const float*)d_in[5];
  const float* a1_ap = (const float*)d_in[6];
  const float* a2_ap = (const float*)d_in[7];
  const float* a1_aa = (const float*)d_in[8];
  const float* a2_aa = (const float*)d_in[9];
  const float* a1_pa = (const float*)d_in[10];
  const float* a2_pa = (const float*)d_in[11];
  const float* a1_pp = (const float*)d_in[12];
  const float* a2_pp = (const float*)d_in[13];
  const float* semW_a = (const float*)d_in[14];
  const float* semb_a = (const float*)d_in[15];
  const float* semq_a = (const float*)d_in[16];
  const float* semW_p = (const float*)d_in[17];
  const float* semb_p = (const float*)d_in[18];
  const float* semq_p = (const float*)d_in[19];
  const float* W2 = (const float*)d_in[20];
  const float* b2 = (const float*)d_in[21];
  const int* ei[4] = {(const int*)d_in[22], (const int*)d_in[23],
                      (const int*)d_in[24], (const int*)d_in[25]};

  // ---- workspace carve ----
  char* w = (char*)d_ws;
  auto alloc = [&](size_t bytes) -> void* {
    void* p = (void*)w;
    w += (bytes + 255) & ~(size_t)255;
    return p;
  };
  const size_t matB = (size_t)NN * DD * sizeof(float);
  float* xA  = (float*)alloc(matB);
  float* xP  = (float*)alloc(matB);
  float* hA  = (float*)alloc(matB);
  float* hP  = (float*)alloc(matB);
  float* eA0 = (float*)alloc(matB);
  float* eA1 = (float*)alloc(matB);
  float* eP0 = (float*)alloc(matB);
  float* eP1 = (float*)alloc(matB);
  // fp16 gather buffers; hA16 aliases xA16 (proj rewrites each call before use)
  __half* xA16 = (__half*)alloc(matB / 2);
  __half* xP16 = (__half*)alloc(matB / 2);
  __half* hA16 = xA16;
  __half* hP16 = xP16;
  // pairbuf (4*E u32 = 12.8 MB) aliases eA0/eA1 (CSR build precedes e-buffer writes)
  unsigned* pairbuf = (unsigned*)eA0;
  int* rowptr[4]; int* tsorted[4];
  for (int r = 0; r < 4; ++r) {
    rowptr[r]  = (int*)alloc((NN + 1) * sizeof(int));
    tsorted[r] = (int*)alloc((size_t)EE * sizeof(int));
  }
  int* bcnt  = (int*)alloc((size_t)4 * NBK * sizeof(int));
  int* bbase = (int*)alloc((size_t)4 * (NBK + 1) * sizeof(int));
  int* bcur  = (int*)alloc((size_t)4 * NBK * sizeof(int));
  float* x1all = (float*)alloc((size_t)4 * NHOP * NN * sizeof(float));
  float* w2all = (float*)alloc((size_t)4 * NHOP * NN * sizeof(float));
  float* h1b[4];
  for (int r = 0; r < 4; ++r) h1b[r] = (float*)alloc(NN * sizeof(float));
  float* psums = (float*)alloc((size_t)2 * NBK * 2 * sizeof(float));
  float* betab = (float*)alloc(64);

  // ---- projections ----
  proj_gemm_relu<<<NN / PBM, 512, 0, stream>>>(x_author, W1_a, b1_a, xA, xA16, NN, 334);
  proj_gemm_relu<<<NN / PBM, 512, 0, stream>>>(x_paper,  W1_p, b1_p, xP, xP16, NN, 512);

  // ---- CSR build (bucket-level counting; no per-node global histogram) ----
  const int NEB = (EE + BINCH - 1) / BINCH;
  zero_i32<<<(4 * NBK + 255) / 256, 256, 0, stream>>>(bcnt, 4 * NBK);
  binCount_kernel<<<dim3(NEB, 4), 256, 0, stream>>>(ei[0], ei[1], ei[2], ei[3], bcnt, EE);
  bucketScan_kernel<<<4, 1024, 0, stream>>>(bcnt, bbase, bcur,
      rowptr[0], rowptr[1], rowptr[2], rowptr[3], EE);
  binA_kernel<<<dim3(NEB, 4), 256, 0, stream>>>(
      ei[0], ei[1], ei[2], ei[3], bcur, pairbuf, EE);
  binB_kernel<<<dim3(NBK, 4), 256, 0, stream>>>(pairbuf, bbase,
      rowptr[0], rowptr[1], rowptr[2], rowptr[3],
      tsorted[0], tsorted[1], tsorted[2], tsorted[3], EE);

  // ---- upfront x1/w2 (all hops) + hop-0 h1 (thread-per-node) ----
  precompute_xw<<<dim3((NN + 255) / 256, 2), 256, 0, stream>>>(
      xA, xP, a1_ap, a2_ap, a1_aa, a2_aa, a1_pa, a2_pa, a1_pp, a2_pp,
      x1all, w2all, h1b[0], h1b[1], h1b[2], h1b[3]);

  // ---- hop loop ----
  const int AGG_GRID = (NN * 64) / 256;
  const int CVEC = NN * DD / 4;
  for (int i = 0; i < NHOP; ++i) {
    #define X1(r) (x1all + ((size_t)(r) * NHOP + i) * NN)
    #define W2P(r) (w2all + ((size_t)(r) * NHOP + i) * NN)
    AggRel r0 = {xA, hP16, X1(0), W2P(0), h1b[0], rowptr[0], tsorted[0], eA0};
    AggRel r1 = {xA, hA16, X1(1), W2P(1), h1b[1], rowptr[1], tsorted[1], eA1};
    AggRel r2 = {xP, hA16, X1(2), W2P(2), h1b[2], rowptr[2], tsorted[2], eP0};
    AggRel r3 = {xP, hP16, X1(3), W2P(3), h1b[3], rowptr[3], tsorted[3], eP1};
    agg4_kernel<<<dim3(AGG_GRID, 4), 256, 0, stream>>>(r0, r1, r2, r3, NN);

    sem_kernel<<<dim3(NN / 64, 2), 256, 0, stream>>>(
        eA0, eA1, eP0, eP1,
        semW_a + (size_t)i * DD * NSEM, semb_a + i * NSEM, semq_a + i * NSEM,
        semW_p + (size_t)i * DD * NSEM, semb_p + i * NSEM, semq_p + i * NSEM,
        psums);
    beta_kernel<<<1, 256, 0, stream>>>(psums, betab, NN / 64, 1.f / NN);

    combine2_kernel<<<dim3((CVEC + 255) / 256, 2), 256, 0, stream>>>(
        (const float4*)eA0, (const float4*)eA1, (const float4*)eP0, (const float4*)eP1,
        betab, (float4*)hA, (float4*)hP, (__half2*)hA16, (__half2*)hP16, CVEC);

    if (i + 1 < NHOP) {
      h1next_kernel<<<(NN + 255) / 256, 256, 0, stream>>>(
          hA, hP,
          a2_ap + (i + 1) * DD, a2_aa + (i + 1) * DD,
          a2_pa + (i + 1) * DD, a2_pp + (i + 1) * DD,
          h1b[0], h1b[1], h1b[2], h1b[3]);
    }
  }

  final_kernel<<<(NN + 255) / 256, 256, 0, stream>>>(hA, W2, b2, (float*)d_out, NN);
}

// Round 7
// 1181.753 us; speedup vs baseline: 2.8820x; 1.0474x over previous
//
#include <hip/hip_runtime.h>
#include <hip/hip_fp16.h>

#define NN 40000
#define DD 64
#define EE 800000
#define NHOP 5
#define NSEM 128
#define NBK 625          // NN/64 buckets for binned scatter
#define BINCH 8192       // edges per binA/binCount block

__device__ __forceinline__ float leaky02(float v) { return v > 0.f ? v : 0.2f * v; }
__device__ __forceinline__ float tanh_fast(float x) {
  return 1.f - 2.f / (__expf(2.f * x) + 1.f);
}
__device__ __forceinline__ float wred(float x) {
  #pragma unroll
  for (int m = 1; m < 64; m <<= 1) x += __shfl_xor(x, m);
  return x;
}

// ---------------- zero kernel ----------------
__global__ void zero_i32(int* __restrict__ p, int n) {
  int i = blockIdx.x * blockDim.x + threadIdx.x;
  if (i < n) p[i] = 0;
}

// ---------------- projection GEMM + bias + relu (f32 out + fp16 copy) ----------------
#define PBM 64
#define PBK 64
__global__ __launch_bounds__(512) void proj_gemm_relu(
    const float* __restrict__ X, const float* __restrict__ W,
    const float* __restrict__ bias, float* __restrict__ out,
    __half* __restrict__ out16, int n, int K)
{
  __shared__ float As[PBM][PBK + 1];
  __shared__ float Bs[PBK][DD];
  int tid = threadIdx.x;
  int tx = tid & 15;
  int ty = tid >> 4;
  int row0 = blockIdx.x * PBM;
  float acc[2][4] = {{0.f}};
  int nk = (K + PBK - 1) / PBK;
  for (int kt = 0; kt < nk; ++kt) {
    int k0 = kt * PBK;
    #pragma unroll
    for (int j = 0; j < 8; ++j) {
      int idx = tid + j * 512;
      int r = idx >> 6, c = idx & 63;
      int gk = k0 + c;
      As[r][c] = (gk < K) ? X[(size_t)(row0 + r) * K + gk] : 0.f;
    }
    #pragma unroll
    for (int j = 0; j < 2; ++j) {
      int idx = tid + j * 512;
      int r = idx >> 4, c4 = idx & 15;
      int gk = k0 + r;
      float4 v = (gk < K) ? ((const float4*)(W + (size_t)gk * DD))[c4]
                          : make_float4(0.f, 0.f, 0.f, 0.f);
      ((float4*)&Bs[r][0])[c4] = v;
    }
    __syncthreads();
    #pragma unroll 8
    for (int kk = 0; kk < PBK; ++kk) {
      float a0 = As[ty * 2][kk];
      float a1 = As[ty * 2 + 1][kk];
      float4 bv = ((float4*)&Bs[kk][0])[tx];
      acc[0][0] = fmaf(a0, bv.x, acc[0][0]);
      acc[0][1] = fmaf(a0, bv.y, acc[0][1]);
      acc[0][2] = fmaf(a0, bv.z, acc[0][2]);
      acc[0][3] = fmaf(a0, bv.w, acc[0][3]);
      acc[1][0] = fmaf(a1, bv.x, acc[1][0]);
      acc[1][1] = fmaf(a1, bv.y, acc[1][1]);
      acc[1][2] = fmaf(a1, bv.z, acc[1][2]);
      acc[1][3] = fmaf(a1, bv.w, acc[1][3]);
    }
    __syncthreads();
  }
  float4 bb = ((const float4*)bias)[tx];
  #pragma unroll
  for (int i = 0; i < 2; ++i) {
    int gr = row0 + ty * 2 + i;
    float4 v;
    v.x = fmaxf(acc[i][0] + bb.x, 0.f);
    v.y = fmaxf(acc[i][1] + bb.y, 0.f);
    v.z = fmaxf(acc[i][2] + bb.z, 0.f);
    v.w = fmaxf(acc[i][3] + bb.w, 0.f);
    ((float4*)(out + (size_t)gr * DD))[tx] = v;
    __half2 p0 = __floats2half2_rn(v.x, v.y);
    __half2 p1 = __floats2half2_rn(v.z, v.w);
    ((__half2*)(out16 + (size_t)gr * DD))[tx * 2 + 0] = p0;
    ((__half2*)(out16 + (size_t)gr * DD))[tx * 2 + 1] = p1;
  }
}

// ---------------- CSR build: bucket counts (LDS-privatized) ----------------
__global__ __launch_bounds__(256) void binCount_kernel(
    const int* __restrict__ e0, const int* __restrict__ e1,
    const int* __restrict__ e2, const int* __restrict__ e3,
    int* __restrict__ bcnt, int e)
{
  int rel = blockIdx.y;
  const int* S = rel == 0 ? e0 : rel == 1 ? e1 : rel == 2 ? e2 : e3;
  __shared__ int cnt[NBK];
  int tid = threadIdx.x;
  for (int b = tid; b < NBK; b += 256) cnt[b] = 0;
  __syncthreads();
  int e0i = blockIdx.x * BINCH;
  int ne = min(BINCH, e - e0i);
  for (int i = tid; i < ne; i += 256) atomicAdd(&cnt[S[e0i + i] >> 6], 1);
  __syncthreads();
  for (int b = tid; b < NBK; b += 256)
    if (cnt[b]) atomicAdd(&bcnt[rel * NBK + b], cnt[b]);
}

// bucket scan -> bucket bases + cursor seed; also sets rowptr[NN]=E
__global__ __launch_bounds__(1024) void bucketScan_kernel(
    const int* __restrict__ bcnt, int* __restrict__ bbase, int* __restrict__ bcur,
    int* __restrict__ rp0, int* __restrict__ rp1, int* __restrict__ rp2,
    int* __restrict__ rp3, int e)
{
  int rel = blockIdx.x;
  __shared__ int sh[1024];
  int t = threadIdx.x;
  int v = (t < NBK) ? bcnt[rel * NBK + t] : 0;
  sh[t] = v;
  __syncthreads();
  for (int off = 1; off < 1024; off <<= 1) {
    int y = (t >= off) ? sh[t - off] : 0;
    __syncthreads();
    sh[t] += y;
    __syncthreads();
  }
  if (t < NBK) {
    int base = sh[t] - v;
    bbase[rel * (NBK + 1) + t] = base;
    bcur[rel * NBK + t] = base;
  }
  if (t == 0) {
    bbase[rel * (NBK + 1) + NBK] = e;
    (rel == 0 ? rp0 : rel == 1 ? rp1 : rel == 2 ? rp2 : rp3)[NN] = e;
  }
}

// pass A: bin edges into buckets, packed u32 = (s&63)<<16 | t
__global__ __launch_bounds__(256) void binA_kernel(
    const int* __restrict__ e0, const int* __restrict__ e1,
    const int* __restrict__ e2, const int* __restrict__ e3,
    int* __restrict__ bcur, unsigned* __restrict__ pairbuf, int e)
{
  int rel = blockIdx.y;
  const int* S = rel == 0 ? e0 : rel == 1 ? e1 : rel == 2 ? e2 : e3;
  const int* T = S + e;
  unsigned* pb = pairbuf + (size_t)rel * e;
  __shared__ int cnt[NBK], base[NBK], cnt2[NBK];
  int tid = threadIdx.x;
  for (int b = tid; b < NBK; b += 256) { cnt[b] = 0; cnt2[b] = 0; }
  __syncthreads();
  int e0i = blockIdx.x * BINCH;
  int ne = min(BINCH, e - e0i);
  for (int i = tid; i < ne; i += 256) atomicAdd(&cnt[S[e0i + i] >> 6], 1);
  __syncthreads();
  for (int b = tid; b < NBK; b += 256)
    base[b] = cnt[b] ? atomicAdd(&bcur[rel * NBK + b], cnt[b]) : 0;
  __syncthreads();
  for (int i = tid; i < ne; i += 256) {
    int s = S[e0i + i];
    int t = T[e0i + i];
    int b = s >> 6;
    int off = atomicAdd(&cnt2[b], 1);
    pb[base[b] + off] = ((unsigned)(s & 63) << 16) | (unsigned)t;
  }
}

// pass B: per bucket — local per-node counts, wave prefix -> rowptr, place targets (u16)
__global__ __launch_bounds__(256) void binB_kernel(
    const unsigned* __restrict__ pairbuf, const int* __restrict__ bbase,
    int* __restrict__ rp0, int* __restrict__ rp1, int* __restrict__ rp2,
    int* __restrict__ rp3,
    unsigned short* __restrict__ ts0, unsigned short* __restrict__ ts1,
    unsigned short* __restrict__ ts2, unsigned short* __restrict__ ts3, int e)
{
  int rel = blockIdx.y;
  int* rowptr = rel == 0 ? rp0 : rel == 1 ? rp1 : rel == 2 ? rp2 : rp3;
  unsigned short* ts = rel == 0 ? ts0 : rel == 1 ? ts1 : rel == 2 ? ts2 : ts3;
  const unsigned* pb = pairbuf + (size_t)rel * e;
  int b = blockIdx.x;
  int bstart = bbase[rel * (NBK + 1) + b];
  int bend   = bbase[rel * (NBK + 1) + b + 1];
  __shared__ int ncnt[64], cur[64];
  int tid = threadIdx.x;
  if (tid < 64) ncnt[tid] = 0;
  __syncthreads();
  for (int i = bstart + tid; i < bend; i += 256)
    atomicAdd(&ncnt[(pb[i] >> 16) & 63], 1);
  __syncthreads();
  if (tid < 64) {                       // wave 0: 64-wide inclusive scan
    int v = ncnt[tid];
    int x = v;
    #pragma unroll
    for (int off = 1; off < 64; off <<= 1) {
      int y = __shfl_up(x, off);
      if (tid >= off) x += y;
    }
    int nb = bstart + x - v;            // exclusive prefix
    rowptr[b * 64 + tid] = nb;
    cur[tid] = nb;
  }
  __syncthreads();
  for (int i = bstart + tid; i < bend; i += 256) {
    unsigned u = pb[i];
    int pos = atomicAdd(&cur[(u >> 16) & 63], 1);
    ts[pos] = (unsigned short)(u & 0xffffu);
  }
}

// ---------------- upfront x1/w2 (all hops) + hop-0 h1 : thread-per-node ----------------
__global__ __launch_bounds__(256) void precompute_xw(
    const float* __restrict__ xA, const float* __restrict__ xP,
    const float* __restrict__ a1_ap, const float* __restrict__ a2_ap,
    const float* __restrict__ a1_aa, const float* __restrict__ a2_aa,
    const float* __restrict__ a1_pa, const float* __restrict__ a2_pa,
    const float* __restrict__ a1_pp, const float* __restrict__ a2_pp,
    float* __restrict__ x1all, float* __restrict__ w2all,
    float* __restrict__ h1_ap, float* __restrict__ h1_aa,
    float* __restrict__ h1_pa, float* __restrict__ h1_pp)
{
  int side = blockIdx.y;
  __shared__ float L[21 * DD];
  int tid = threadIdx.x;
  {
    const float* s0 = side ? a1_pa : a1_ap;
    const float* s1 = side ? a2_pa : a2_ap;
    const float* s2 = side ? a1_pp : a1_aa;
    const float* s3 = side ? a2_pp : a2_aa;
    const float* ex = side ? a2_ap : a2_pa;   // hop-0 cross-side extra
    for (int i = tid; i < 21 * DD; i += 256) {
      int k = i >> 6, d = i & 63;
      const float* src = (k < 5) ? s0 : (k < 10) ? s1 : (k < 15) ? s2 : (k < 20) ? s3 : ex;
      int hop = (k < 20) ? (k % 5) : 0;
      L[i] = src[hop * DD + d];
    }
  }
  __syncthreads();
  int j = blockIdx.x * 256 + tid;
  if (j >= NN) return;
  const float4* x4 = (const float4*)((side ? xP : xA) + (size_t)j * DD);
  float acc[21];
  #pragma unroll
  for (int k = 0; k < 21; ++k) acc[k] = 0.f;
  #pragma unroll
  for (int d0 = 0; d0 < 16; ++d0) {
    float4 v = x4[d0];
    #pragma unroll
    for (int c = 0; c < 4; ++c) {
      int d = d0 * 4 + c;
      float xv = (&v.x)[c];
      #pragma unroll
      for (int k = 0; k < 21; ++k) acc[k] = fmaf(xv, L[k * DD + d], acc[k]);
    }
  }
  int relA = side ? 2 : 0;
  #pragma unroll
  for (int i = 0; i < NHOP; ++i) {
    x1all[((size_t)(relA + 0) * NHOP + i) * NN + j] = acc[0 * 5 + i];
    w2all[((size_t)(relA + 0) * NHOP + i) * NN + j] =
        __expf(leaky02(acc[0 * 5 + i] + acc[1 * 5 + i]));
    x1all[((size_t)(relA + 1) * NHOP + i) * NN + j] = acc[2 * 5 + i];
    w2all[((size_t)(relA + 1) * NHOP + i) * NN + j] =
        __expf(leaky02(acc[2 * 5 + i] + acc[3 * 5 + i]));
  }
  if (side) { h1_pp[j] = acc[15]; h1_ap[j] = acc[20]; }
  else      { h1_aa[j] = acc[15]; h1_pa[j] = acc[20]; }
}

// ---------------- fused edge aggregation: 2-edges/step half2 + XCD partition ----------------
struct AggRel {
  const float* x; const __half2* h2; const float* x1; const float* w2; const float* h1;
  const int* rowptr; const unsigned short* tsorted; float* out;
};

// 1D grid of NN blocks (4 rel x NN/4 node-blocks, 4 nodes/block).
// group bit = (bid>>2)&1 == XCD index bit 2 under round-robin mapping:
//   XCDs 0-3 run relations {1,2} (gather hA16), XCDs 4-7 run {0,3} (gather hP16)
// -> each XCD's 4MB L2 caches only one 5MB h16 buffer.
__global__ __launch_bounds__(256) void agg4_kernel(AggRel r0, AggRel r1, AggRel r2,
                                                   AggRel r3, int n)
{
  int bid = blockIdx.x;
  int g = (bid >> 2) & 1;
  int u = (bid >> 3) * 4 + (bid & 3);       // 0 .. n/2-1
  int half = n >> 2;                        // blocks per relation (10000)
  int relsel = u >= half;
  int nodeblk = relsel ? (u - half) : u;
  AggRel R;
  if (g == 0) R = relsel ? r2 : r1;
  else        R = relsel ? r3 : r0;

  int wid = nodeblk * 4 + (threadIdx.x >> 6);
  int lane = threadIdx.x & 63;
  int pair = lane >> 5;        // 0: even edges, 1: odd edges
  int c2 = lane & 31;          // half2 column index (cols 2*c2, 2*c2+1)

  int beg = R.rowptr[wid], end = R.rowptr[wid + 1];
  float x1i = R.x1[wid];
  float2 accA = make_float2(0.f, 0.f), accB = make_float2(0.f, 0.f);
  float wsumL = 0.f;
  for (int c = beg; c < end; c += 64) {
    int idx = c + lane;
    int t = 0;
    float wv = 0.f;
    if (idx < end) {
      t = R.tsorted[idx];
      wv = __expf(leaky02(x1i + R.h1[t]));
    }
    wsumL += wv;
    int ne = min(64, end - c);
    int j = 0;
    for (; j + 4 <= ne; j += 4) {
      int s0 = j + pair, s1 = j + 2 + pair;
      int t0 = __shfl(t, s0), t1 = __shfl(t, s1);
      float w0 = __shfl(wv, s0), w1 = __shfl(wv, s1);
      float2 f0 = __half22float2(R.h2[((unsigned)t0 << 5) + c2]);
      float2 f1 = __half22float2(R.h2[((unsigned)t1 << 5) + c2]);
      accA.x = fmaf(w0, f0.x, accA.x);
      accA.y = fmaf(w0, f0.y, accA.y);
      accB.x = fmaf(w1, f1.x, accB.x);
      accB.y = fmaf(w1, f1.y, accB.y);
    }
    for (; j < ne; j += 2) {
      int s0 = j + pair;                     // phantom edge (s0==ne) has wv==0
      int t0 = __shfl(t, s0);
      float w0 = __shfl(wv, s0);
      float2 f0 = __half22float2(R.h2[((unsigned)t0 << 5) + c2]);
      accA.x = fmaf(w0, f0.x, accA.x);
      accA.y = fmaf(w0, f0.y, accA.y);
    }
  }
  float wsum = wred(wsumL);
  float2 acc;
  acc.x = accA.x + accB.x;
  acc.y = accA.y + accB.y;
  acc.x += __shfl_xor(acc.x, 32);            // fold odd-edge half into even half
  acc.y += __shfl_xor(acc.y, 32);
  if (pair == 0) {
    float w2v = R.w2[wid];
    float inv = 1.f / (wsum + w2v);
    float2 xv = ((const float2*)(R.x + (size_t)wid * DD))[c2];
    float2 o;
    o.x = fmaf(w2v, xv.x, acc.x) * inv;
    o.y = fmaf(w2v, xv.y, acc.y) * inv;
    ((float2*)(R.out + (size_t)wid * DD))[c2] = o;
  }
}

// ---------------- semantic attention partial sums ----------------
__global__ __launch_bounds__(256) void sem_kernel(
    const float* __restrict__ eA0, const float* __restrict__ eA1,
    const float* __restrict__ eP0, const float* __restrict__ eP1,
    const float* __restrict__ Wa, const float* __restrict__ ba, const float* __restrict__ qa,
    const float* __restrict__ Wp, const float* __restrict__ bp, const float* __restrict__ qp,
    float* __restrict__ psums)
{
  int side = blockIdx.y;
  const float* e0 = side ? eP0 : eA0;
  const float* e1 = side ? eP1 : eA1;
  const float* W = side ? Wp : Wa;
  const float* b = side ? bp : ba;
  const float* q = side ? qp : qa;

  __shared__ float Ws[DD * NSEM];
  __shared__ float zs[8][2][DD];
  __shared__ float red0[256], red1[256];
  int tid = threadIdx.x;
  {
    const float4* W4 = (const float4*)W;
    float4* Ws4 = (float4*)Ws;
    #pragma unroll
    for (int j = 0; j < 8; ++j) Ws4[tid + j * 256] = W4[tid + j * 256];
  }
  int slot = tid >> 7;
  int k = tid & 127;
  float bk = b[k], qk = q[k];
  int base = blockIdx.x * 64;
  float sum0 = 0.f, sum1 = 0.f;
  for (int it = 0; it < 8; ++it) {
    #pragma unroll
    for (int j = 0; j < 4; ++j) {
      int idx = tid + j * 256;
      int nn = idx >> 7, m = (idx >> 6) & 1, d = idx & 63;
      int node = base + it * 8 + nn;
      zs[nn][m][d] = (m ? e1 : e0)[(size_t)node * DD + d];
    }
    __syncthreads();
    float acc[4][2];
    #pragma unroll
    for (int nn = 0; nn < 4; ++nn) { acc[nn][0] = bk; acc[nn][1] = bk; }
    #pragma unroll 8
    for (int d = 0; d < DD; ++d) {
      float w = Ws[d * NSEM + k];
      #pragma unroll
      for (int nn = 0; nn < 4; ++nn) {
        acc[nn][0] = fmaf(zs[slot * 4 + nn][0][d], w, acc[nn][0]);
        acc[nn][1] = fmaf(zs[slot * 4 + nn][1][d], w, acc[nn][1]);
      }
    }
    #pragma unroll
    for (int nn = 0; nn < 4; ++nn) {
      sum0 += tanh_fast(acc[nn][0]) * qk;
      sum1 += tanh_fast(acc[nn][1]) * qk;
    }
    __syncthreads();
  }
  red0[tid] = sum0;
  red1[tid] = sum1;
  __syncthreads();
  for (int off = 128; off; off >>= 1) {
    if (tid < off) { red0[tid] += red0[tid + off]; red1[tid] += red1[tid + off]; }
    __syncthreads();
  }
  if (tid == 0) {
    int idx = (side * gridDim.x + blockIdx.x) * 2;
    psums[idx + 0] = red0[0];
    psums[idx + 1] = red1[0];
  }
}

__global__ __launch_bounds__(256) void beta_kernel(const float* __restrict__ psums,
    float* __restrict__ beta, int nblk, float invn)
{
  __shared__ float s[4][256];
  int t = threadIdx.x;
  float a0 = 0.f, a1 = 0.f, p0 = 0.f, p1 = 0.f;
  for (int i = t; i < nblk; i += 256) {
    a0 += psums[i * 2];
    a1 += psums[i * 2 + 1];
    p0 += psums[(nblk + i) * 2];
    p1 += psums[(nblk + i) * 2 + 1];
  }
  s[0][t] = a0; s[1][t] = a1; s[2][t] = p0; s[3][t] = p1;
  __syncthreads();
  for (int off = 128; off; off >>= 1) {
    if (t < off) {
      s[0][t] += s[0][t + off]; s[1][t] += s[1][t + off];
      s[2][t] += s[2][t + off]; s[3][t] += s[3][t + off];
    }
    __syncthreads();
  }
  if (t == 0) {
    float m0 = s[0][0] * invn, m1 = s[1][0] * invn;
    float mx = fmaxf(m0, m1);
    float x0 = __expf(m0 - mx), x1 = __expf(m1 - mx);
    float inv = 1.f / (x0 + x1);
    beta[0] = x0 * inv; beta[1] = x1 * inv;
    m0 = s[2][0] * invn; m1 = s[3][0] * invn;
    mx = fmaxf(m0, m1);
    x0 = __expf(m0 - mx); x1 = __expf(m1 - mx);
    inv = 1.f / (x0 + x1);
    beta[2] = x0 * inv; beta[3] = x1 * inv;
  }
}

// ---------------- combine both sides (pure elementwise, float4) ----------------
__global__ void combine2_kernel(const float4* __restrict__ eA0, const float4* __restrict__ eA1,
    const float4* __restrict__ eP0, const float4* __restrict__ eP1,
    const float* __restrict__ beta, float4* __restrict__ hA, float4* __restrict__ hP,
    __half2* __restrict__ hA16, __half2* __restrict__ hP16, int nvec)
{
  int side = blockIdx.y;
  int i = blockIdx.x * 256 + threadIdx.x;
  if (i >= nvec) return;
  float b0 = beta[side * 2], b1 = beta[side * 2 + 1];
  float4 v0 = (side ? eP0 : eA0)[i];
  float4 v1 = (side ? eP1 : eA1)[i];
  float4 r;
  float t;
  t = b0 * v0.x + b1 * v1.x; r.x = t > 0.f ? t : (__expf(t) - 1.f);
  t = b0 * v0.y + b1 * v1.y; r.y = t > 0.f ? t : (__expf(t) - 1.f);
  t = b0 * v0.z + b1 * v1.z; r.z = t > 0.f ? t : (__expf(t) - 1.f);
  t = b0 * v0.w + b1 * v1.w; r.w = t > 0.f ? t : (__expf(t) - 1.f);
  (side ? hP : hA)[i] = r;
  (side ? hP16 : hA16)[i * 2 + 0] = __floats2half2_rn(r.x, r.y);
  (side ? hP16 : hA16)[i * 2 + 1] = __floats2half2_rn(r.z, r.w);
}

// ---------------- next-hop h1 dots (thread-per-node) ----------------
__global__ __launch_bounds__(256) void h1next_kernel(
    const float* __restrict__ hA, const float* __restrict__ hP,
    const float* __restrict__ a2_ap_n, const float* __restrict__ a2_aa_n,
    const float* __restrict__ a2_pa_n, const float* __restrict__ a2_pp_n,
    float* __restrict__ h1_ap, float* __restrict__ h1_aa,
    float* __restrict__ h1_pa, float* __restrict__ h1_pp)
{
  __shared__ float L[4][DD];
  int tid = threadIdx.x;
  if (tid < 4 * DD) {
    int k = tid >> 6, d = tid & 63;
    const float* src = k == 0 ? a2_ap_n : k == 1 ? a2_aa_n : k == 2 ? a2_pa_n : a2_pp_n;
    L[k][d] = src[d];
  }
  __syncthreads();
  int j = blockIdx.x * 256 + tid;
  if (j >= NN) return;
  const float4* ha4 = (const float4*)(hA + (size_t)j * DD);
  const float4* hp4 = (const float4*)(hP + (size_t)j * DD);
  float s0 = 0.f, s1 = 0.f, s2 = 0.f, s3 = 0.f;
  #pragma unroll
  for (int d0 = 0; d0 < 16; ++d0) {
    float4 a = ha4[d0];
    float4 p = hp4[d0];
    #pragma unroll
    for (int c = 0; c < 4; ++c) {
      int d = d0 * 4 + c;
      float av = (&a.x)[c], pv = (&p.x)[c];
      s0 = fmaf(pv, L[0][d], s0);   // h1_ap = hP . a2_ap
      s1 = fmaf(av, L[1][d], s1);   // h1_aa = hA . a2_aa
      s2 = fmaf(av, L[2][d], s2);   // h1_pa = hA . a2_pa
      s3 = fmaf(pv, L[3][d], s3);   // h1_pp = hP . a2_pp
    }
  }
  h1_ap[j] = s0;
  h1_aa[j] = s1;
  h1_pa[j] = s2;
  h1_pp[j] = s3;
}

// ---------------- final projection ----------------
__global__ void final_kernel(const float* __restrict__ hA, const float* __restrict__ W2,
    const float* __restrict__ b2, float* __restrict__ out, int n)
{
  int j = blockIdx.x * blockDim.x + threadIdx.x;
  if (j >= n) return;
  float acc0 = b2[0], acc1 = b2[1], acc2 = b2[2], acc3 = b2[3];
  const float4* hrow = (const float4*)(hA + (size_t)j * DD);
  #pragma unroll
  for (int d4 = 0; d4 < 16; ++d4) {
    float4 v = hrow[d4];
    #pragma unroll
    for (int c = 0; c < 4; ++c) {
      int d = d4 * 4 + c;
      float vv = (&v.x)[c];
      acc0 = fmaf(vv, W2[d * 4 + 0], acc0);
      acc1 = fmaf(vv, W2[d * 4 + 1], acc1);
      acc2 = fmaf(vv, W2[d * 4 + 2], acc2);
      acc3 = fmaf(vv, W2[d * 4 + 3], acc3);
    }
  }
  ((float4*)out)[j] = make_float4(acc0, acc1, acc2, acc3);
}

extern "C" void kernel_launch(void* const* d_in, const int* in_sizes, int n_in,
                              void* d_out, int out_size, void* d_ws, size_t ws_size,
                              hipStream_t stream)
{
  const float* x_author = (const float*)d_in[0];
  const float* x_paper  = (const float*)d_in[1];
  const float* W1_a = (const float*)d_in[2];
  const float* b1_a = (const float*)d_in[3];
  const float* W1_p = (const float*)d_in[4];
  const float* b1_p = (const float*)d_in[5];
  const float* a1_ap = (const float*)d_in[6];
  const float* a2_ap = (const float*)d_in[7];
  const float* a1_aa = (const float*)d_in[8];
  const float* a2_aa = (const float*)d_in[9];
  const float* a1_pa = (const float*)d_in[10];
  const float* a2_pa = (const float*)d_in[11];
  const float* a1_pp = (const float*)d_in[12];
  const float* a2_pp = (const float*)d_in[13];
  const float* semW_a = (const float*)d_in[14];
  const float* semb_a = (const float*)d_in[15];
  const float* semq_a = (const float*)d_in[16];
  const float* semW_p = (const float*)d_in[17];
  const float* semb_p = (const float*)d_in[18];
  const float* semq_p = (const float*)d_in[19];
  const float* W2 = (const float*)d_in[20];
  const float* b2 = (const float*)d_in[21];
  const int* ei[4] = {(const int*)d_in[22], (const int*)d_in[23],
                      (const int*)d_in[24], (const int*)d_in[25]};

  // ---- workspace carve ----
  char* w = (char*)d_ws;
  auto alloc = [&](size_t bytes) -> void* {
    void* p = (void*)w;
    w += (bytes + 255) & ~(size_t)255;
    return p;
  };
  const size_t matB = (size_t)NN * DD * sizeof(float);
  float* xA  = (float*)alloc(matB);
  float* xP  = (float*)alloc(matB);
  float* hA  = (float*)alloc(matB);
  float* hP  = (float*)alloc(matB);
  float* eA0 = (float*)alloc(matB);
  float* eA1 = (float*)alloc(matB);
  float* eP0 = (float*)alloc(matB);
  float* eP1 = (float*)alloc(matB);
  // fp16 gather buffers; hA16 aliases xA16 (proj rewrites each call before use)
  __half* xA16 = (__half*)alloc(matB / 2);
  __half* xP16 = (__half*)alloc(matB / 2);
  __half* hA16 = xA16;
  __half* hP16 = xP16;
  // pairbuf (4*E u32 = 12.8 MB) aliases eA0/eA1 (CSR build precedes e-buffer writes)
  unsigned* pairbuf = (unsigned*)eA0;
  int* rowptr[4]; unsigned short* tsorted[4];
  for (int r = 0; r < 4; ++r) {
    rowptr[r]  = (int*)alloc((NN + 1) * sizeof(int));
    tsorted[r] = (unsigned short*)alloc((size_t)EE * sizeof(unsigned short));
  }
  int* bcnt  = (int*)alloc((size_t)4 * NBK * sizeof(int));
  int* bbase = (int*)alloc((size_t)4 * (NBK + 1) * sizeof(int));
  int* bcur  = (int*)alloc((size_t)4 * NBK * sizeof(int));
  float* x1all = (float*)alloc((size_t)4 * NHOP * NN * sizeof(float));
  float* w2all = (float*)alloc((size_t)4 * NHOP * NN * sizeof(float));
  float* h1b[4];
  for (int r = 0; r < 4; ++r) h1b[r] = (float*)alloc(NN * sizeof(float));
  float* psums = (float*)alloc((size_t)2 * NBK * 2 * sizeof(float));
  float* betab = (float*)alloc(64);

  // ---- projections ----
  proj_gemm_relu<<<NN / PBM, 512, 0, stream>>>(x_author, W1_a, b1_a, xA, xA16, NN, 334);
  proj_gemm_relu<<<NN / PBM, 512, 0, stream>>>(x_paper,  W1_p, b1_p, xP, xP16, NN, 512);

  // ---- CSR build (bucket-level counting; no per-node global histogram) ----
  const int NEB = (EE + BINCH - 1) / BINCH;
  zero_i32<<<(4 * NBK + 255) / 256, 256, 0, stream>>>(bcnt, 4 * NBK);
  binCount_kernel<<<dim3(NEB, 4), 256, 0, stream>>>(ei[0], ei[1], ei[2], ei[3], bcnt, EE);
  bucketScan_kernel<<<4, 1024, 0, stream>>>(bcnt, bbase, bcur,
      rowptr[0], rowptr[1], rowptr[2], rowptr[3], EE);
  binA_kernel<<<dim3(NEB, 4), 256, 0, stream>>>(
      ei[0], ei[1], ei[2], ei[3], bcur, pairbuf, EE);
  binB_kernel<<<dim3(NBK, 4), 256, 0, stream>>>(pairbuf, bbase,
      rowptr[0], rowptr[1], rowptr[2], rowptr[3],
      tsorted[0], tsorted[1], tsorted[2], tsorted[3], EE);

  // ---- upfront x1/w2 (all hops) + hop-0 h1 (thread-per-node) ----
  precompute_xw<<<dim3((NN + 255) / 256, 2), 256, 0, stream>>>(
      xA, xP, a1_ap, a2_ap, a1_aa, a2_aa, a1_pa, a2_pa, a1_pp, a2_pp,
      x1all, w2all, h1b[0], h1b[1], h1b[2], h1b[3]);

  // ---- hop loop ----
  const int CVEC = NN * DD / 4;
  for (int i = 0; i < NHOP; ++i) {
    #define X1(r) (x1all + ((size_t)(r) * NHOP + i) * NN)
    #define W2P(r) (w2all + ((size_t)(r) * NHOP + i) * NN)
    AggRel r0 = {xA, (const __half2*)hP16, X1(0), W2P(0), h1b[0], rowptr[0], tsorted[0], eA0};
    AggRel r1 = {xA, (const __half2*)hA16, X1(1), W2P(1), h1b[1], rowptr[1], tsorted[1], eA1};
    AggRel r2 = {xP, (const __half2*)hA16, X1(2), W2P(2), h1b[2], rowptr[2], tsorted[2], eP0};
    AggRel r3 = {xP, (const __half2*)hP16, X1(3), W2P(3), h1b[3], rowptr[3], tsorted[3], eP1};
    agg4_kernel<<<NN, 256, 0, stream>>>(r0, r1, r2, r3, NN);

    sem_kernel<<<dim3(NN / 64, 2), 256, 0, stream>>>(
        eA0, eA1, eP0, eP1,
        semW_a + (size_t)i * DD * NSEM, semb_a + i * NSEM, semq_a + i * NSEM,
        semW_p + (size_t)i * DD * NSEM, semb_p + i * NSEM, semq_p + i * NSEM,
        psums);
    beta_kernel<<<1, 256, 0, stream>>>(psums, betab, NN / 64, 1.f / NN);

    combine2_kernel<<<dim3((CVEC + 255) / 256, 2), 256, 0, stream>>>(
        (const float4*)eA0, (const float4*)eA1, (const float4*)eP0, (const float4*)eP1,
        betab, (float4*)hA, (float4*)hP, (__half2*)hA16, (__half2*)hP16, CVEC);

    if (i + 1 < NHOP) {
      h1next_kernel<<<(NN + 255) / 256, 256, 0, stream>>>(
          hA, hP,
          a2_ap + (i + 1) * DD, a2_aa + (i + 1) * DD,
          a2_pa + (i + 1) * DD, a2_pp + (i + 1) * DD,
          h1b[0], h1b[1], h1b[2], h1b[3]);
    }
  }

  final_kernel<<<(NN + 255) / 256, 256, 0, stream>>>(hA, W2, b2, (float*)d_out, NN);
}